// Round 8
// baseline (2451.892 us; speedup 1.0000x reference)
//
#include <hip/hip_runtime.h>
#include <hip/hip_bf16.h>
#include <math.h>

#define BTOT   16384
#define NLAYER 24
#define HID    192
#define NDIN   12
#define NBASE  66
#define EPSP   1e-3f
#define EPB    32        // elements per block; 1024 threads; grid 512

// ---------------- LDS layout (bytes), 115,232 total (1 block/CU) ------
#define EST 200          // j/k stride (shorts) for sH1b/sGb rows
#define OB_H1  0         // ushort[32*200]  12800 : h1 bf16 [e][k]
#define OB_G   12800     // ushort[192*200] 76800 : h2 (rows 0-31) then G [col][j]
#define OB_R   89600     // float[72*32]     9216 : cotangent rows [rt][e]
#define OB_W1  98816     // ushort[192*8]    3072 : W1 bf16 rows padded to 8
#define OB_W3  101888    // ushort[192*16]   6144 : W3 bf16 [j][t-pairs]
#define OB_PRM 108032    // float[12*32]     1536 : prm sums; then tf@2i, es@2i+1
#define OB_GZ  109568    // float[6*192]     4608 : g_z1 sums [i][col] (atomics)
#define OB_Z1  114176    // float[6*32]       768 : z[6..12) for next F1
#define OB_LD  114944    // float[32]         128 : logdet acc
#define OB_ZQ  115072    // float[32]         128 : sum z^2
#define OB_RED 115200    // float[8]           32
#define SMEM_BYTES 115232

typedef __attribute__((ext_vector_type(8))) short s8v;
typedef __attribute__((ext_vector_type(4))) float f4v;
#define MFMA16(a,b,c) __builtin_amdgcn_mfma_f32_16x16x32_bf16(a,b,c,0,0,0)

__device__ __forceinline__ unsigned short f2bf(float f) {
  unsigned u = __builtin_bit_cast(unsigned, f);
  u += 0x7fffu + ((u >> 16) & 1u);          // RNE
  return (unsigned short)(u >> 16);
}
__device__ __forceinline__ float bf2f(unsigned short h) {
  unsigned u = ((unsigned)h) << 16;
  return __builtin_bit_cast(float, u);
}
__device__ __forceinline__ unsigned pk2(float a, float b) {
  return (unsigned)f2bf(a) | ((unsigned)f2bf(b) << 16);
}
__device__ __forceinline__ float blo(unsigned u) { return bf2f((unsigned short)(u & 0xffff)); }
__device__ __forceinline__ float bhi(unsigned u) { return bf2f((unsigned short)(u >> 16)); }

// ---------------------------------------------------------------------
// prep: W2 -> bf16 (orig layout) and bf16 transpose, into workspace.
__global__ void prep_kernel(const float* __restrict__ W2,
                            unsigned short* __restrict__ w2b,
                            unsigned short* __restrict__ w2t) {
  int idx = blockIdx.x * 256 + threadIdx.x;   // 884736 exact
  int l   = idx / (HID * HID);
  int rem = idx - l * HID * HID;
  int k   = rem / HID;
  int j   = rem - k * HID;
  w2b[idx] = f2bf(W2[idx]);                         // [l][j][k]
  w2t[idx] = f2bf(W2[l * HID * HID + j * HID + k]); // [l][k][j]
}

// ---------------------------------------------------------------------
// flow_kernel: ONE 1024-thread block per 32 elements (grid 512).
// 16 waves co-resident per CU by construction (multi-block residency
// never materialized in R3-R7: occupancy pinned at 24% = 8 waves).
// Scalar phases: e = tid&31, slab = tid>>5 (6-wide j chunk).
// V3 GEMM: 192 k x 192 cols (col = r*32+e) x 192 j; 12x12 tiles,
// wave w: mtg=(w&3)*3, ntg=(w>>2)*3 -> 3x3 tiles (same regs as R7, ~92).
// 1024 threads force VGPR<=128; natural demand ~92 so no spill expected.
__global__ __launch_bounds__(1024) void flow_kernel(
    float* __restrict__ yz, float* __restrict__ jp,
    const float* __restrict__ W1, const float* __restrict__ b1,
    const float* __restrict__ b2,
    const float* __restrict__ W3, const float* __restrict__ b3,
    const unsigned short* __restrict__ w2b,
    const unsigned short* __restrict__ w2t,
    float* __restrict__ ws_sum, float* __restrict__ out_lp) {
  extern __shared__ char smraw[];
  unsigned short* sH1b = (unsigned short*)(smraw + OB_H1);
  unsigned short* sGb  = (unsigned short*)(smraw + OB_G);
  unsigned short* sW3  = (unsigned short*)(smraw + OB_W3);
  float* sR   = (float*)(smraw + OB_R);
  float* sPRM = (float*)(smraw + OB_PRM);
  float* sGZ  = (float*)(smraw + OB_GZ);
  float* sZ1  = (float*)(smraw + OB_Z1);
  float* sLD  = (float*)(smraw + OB_LD);
  float* sZQ  = (float*)(smraw + OB_ZQ);
  float* sRed = (float*)(smraw + OB_RED);

  const int tid  = threadIdx.x;
  const int lane = tid & 63;
  const int w    = __builtin_amdgcn_readfirstlane(tid >> 6);  // 0..15
  const int e    = tid & 31;                     // element (scalar phases)
  const int s6   = (tid >> 5) * 6;               // 6-wide j slab
  const int lm   = lane & 15, lq = lane >> 4;    // MFMA lane coords
  const int mtg  = (w & 3) * 3;                  // m-tile base {0,3,6,9}
  const int ntg  = (w >> 2) * 3;                 // n-tile base {0,3,6,9}
  const int blk  = blockIdx.x;

  // ---- init ----
  float z_a = 0.f, z_b = 0.f;     // z[i], z[6+i] held by tid<192 (i=tid>>5)
  if (tid < 192) {
    int i = tid >> 5;
    z_a = yz[(blk * EPB + e) * 12 + i];
    z_b = yz[(blk * EPB + e) * 12 + 6 + i];
    sZ1[i * EPB + e] = z_b;
  }
  if (tid < 32) { sLD[tid] = 0.f; sZQ[tid] = 0.f; }
  if (tid == 0) sRed[0] = 0.f;
  for (int idx = tid; idx < 1152; idx += 1024) sGZ[idx] = 0.f;
  for (int idx = tid; idx < 72 * EPB; idx += 1024) {
    int rt = idx >> 5, ee = idx & 31;
    sR[idx] = jp[(blk * EPB + ee) * 72 + rt];
  }
  __syncthreads();

  unsigned m2 = 0;   // 6-bit relu mask for this thread's h2 chunk

  for (int l = NLAYER - 1; l >= 0; --l) {
    const float* W1l = W1 + l * HID * 6;
    const float* b1l = b1 + l * HID;
    const float* b2l = b2 + l * HID;
    const float* W3l = W3 + l * NDIN * HID;
    const float* b3l = b3 + l * NDIN;
    const unsigned short* w2bl = w2b + l * HID * HID;
    const unsigned short* w2tl = w2t + l * HID * HID;

    // ======== F1: stage W1/W3 bf16, zero sPRM, h1 = relu(W1 z1 + b1) ====
    if (tid < 192) {
      const float* wr = W1l + tid * 6;
      uint4 pk;
      pk.x = pk2(wr[0], wr[1]); pk.y = pk2(wr[2], wr[3]);
      pk.z = pk2(wr[4], wr[5]); pk.w = 0;
      *(uint4*)(smraw + OB_W1 + tid * 16) = pk;
      unsigned* wd = (unsigned*)&sW3[tid * 16];   // W3 [j][t-pairs] bf16
      #pragma unroll
      for (int c = 0; c < 6; ++c)
        wd[c] = pk2(W3l[(2 * c) * HID + tid], W3l[(2 * c + 1) * HID + tid]);
    }
    if (tid < 384) sPRM[tid] = 0.f;
    {
      float z1v[6];
      #pragma unroll
      for (int i = 0; i < 6; ++i) z1v[i] = sZ1[i * EPB + e];
      #pragma unroll
      for (int jj = 0; jj < 6; ++jj) {
        int j = s6 + jj;
        float acc = b1l[j];
        #pragma unroll
        for (int i = 0; i < 6; ++i) acc = fmaf(W1l[j * 6 + i], z1v[i], acc);
        sH1b[e * EST + j] = f2bf(fmaxf(acc, 0.f));
      }
    }
    __syncthreads();

    // ======== S1: F2 via MFMA (waves 0-7): h2 -> sGb rows 0..31 =========
    if (w < 8) {
      const int nt1 = w >> 2;                    // 0..1 (32 cols)
      f4v acc3[3] = {{0,0,0,0},{0,0,0,0},{0,0,0,0}};
      #pragma unroll 2
      for (int kk = 0; kk < 6; ++kk) {
        int jo = kk * 32 + lq * 8;
        s8v B = *(const s8v*)&sH1b[(nt1 * 16 + lm) * EST + jo];
        #pragma unroll
        for (int p = 0; p < 3; ++p) {
          s8v A = *(const s8v*)(w2bl + ((mtg + p) * 16 + lm) * HID + jo);
          acc3[p] = MFMA16(A, B, acc3[p]);
        }
      }
      int e2 = nt1 * 16 + lm;
      #pragma unroll
      for (int p = 0; p < 3; ++p) {
        int jb2 = (mtg + p) * 16 + lq * 4;
        float h0 = fmaxf(acc3[p][0] + b2l[jb2],     0.f);
        float h1 = fmaxf(acc3[p][1] + b2l[jb2 + 1], 0.f);
        float h2 = fmaxf(acc3[p][2] + b2l[jb2 + 2], 0.f);
        float h3 = fmaxf(acc3[p][3] + b2l[jb2 + 3], 0.f);
        unsigned* dst = (unsigned*)sGb + ((e2 * EST + jb2) >> 1);
        dst[0] = pk2(h0, h1);
        dst[1] = pk2(h2, h3);
      }
    }
    __syncthreads();

    // ======== S2: prm partials (fp32 W3 global) + reduce; capture m2 ====
    {
      const unsigned* hp = (const unsigned*)&sGb[e * EST + s6];
      unsigned h2d0 = hp[0], h2d1 = hp[1], h2d2 = hp[2];
      float h2v[6] = { blo(h2d0), bhi(h2d0), blo(h2d1),
                       bhi(h2d1), blo(h2d2), bhi(h2d2) };
      m2  = (h2d0 & 0xffffu ? 1u : 0u)       | (h2d0 >> 16 ? 2u : 0u)
          | (h2d1 & 0xffffu ? 4u : 0u)       | (h2d1 >> 16 ? 8u : 0u)
          | (h2d2 & 0xffffu ? 16u : 0u)      | (h2d2 >> 16 ? 32u : 0u);
      #pragma unroll
      for (int t = 0; t < 12; ++t) {
        const float* w3r = W3l + t * HID + s6;
        float pp = 0.f;
        #pragma unroll
        for (int jj = 0; jj < 6; ++jj) pp = fmaf(w3r[jj], h2v[jj], pp);
        pp += __shfl_xor(pp, 32);              // merge the wave's 2 slabs
        if (lane < 32) atomicAdd(&sPRM[t * EPB + lane], pp);
      }
    }
    __syncthreads();

    // ======== U: coupling update; sPRM becomes tf@(2i), es@(2i+1) =======
    if (tid < 192) {
      int i = tid >> 5;
      float sh = b3l[2 * i]     + sPRM[(2 * i) * EPB + e];
      float sr = b3l[2 * i + 1] + sPRM[(2 * i + 1) * EPB + e];
      float s  = 2.f * tanhf(0.5f * sr);
      float es = expf(s), en = expf(-s);
      float tv = z_a - sh;
      z_a = z_b;
      z_b = tv * en;
      sZ1[i * EPB + e] = z_b;
      sPRM[(2 * i) * EPB + e]     = tv * (1.f - 0.25f * s * s);  // tf
      sPRM[(2 * i + 1) * EPB + e] = es;                          // es
      atomicAdd(&sLD[e], -s);
    }
    __syncthreads();

    // ======== V2 (all 6 rows): G[col=r*32+e][j] = mask2 .* (W3^T gp_r) ==
    {
      float tf[6];
      #pragma unroll
      for (int i = 0; i < 6; ++i) tf[i] = sPRM[(2 * i) * EPB + e];
      float weff[6][6];
      #pragma unroll
      for (int jj = 0; jj < 6; ++jj) {
        const unsigned* wd = (const unsigned*)&sW3[(s6 + jj) * 16];
        #pragma unroll
        for (int c = 0; c < 6; ++c) {
          unsigned wv = wd[c];
          weff[jj][c] = fmaf(tf[c], bhi(wv), blo(wv));
        }
      }
      #pragma unroll
      for (int r = 0; r < 6; ++r) {
        float g[6] = {0.f, 0.f, 0.f, 0.f, 0.f, 0.f};
        #pragma unroll
        for (int c = 0; c < 6; ++c) {
          float r1 = sR[(r * 12 + c) * EPB + e];
          #pragma unroll
          for (int jj = 0; jj < 6; ++jj)
            g[jj] = fmaf(weff[jj][c], r1, g[jj]);
        }
        unsigned* dst = (unsigned*)sGb + (((r * EPB + e) * EST + s6) >> 1);
        float v0 = (m2 & 1u)  ? g[0] : 0.f;
        float v1 = (m2 & 2u)  ? g[1] : 0.f;
        float v2 = (m2 & 4u)  ? g[2] : 0.f;
        float v3 = (m2 & 8u)  ? g[3] : 0.f;
        float v4 = (m2 & 16u) ? g[4] : 0.f;
        float v5 = (m2 & 32u) ? g[5] : 0.f;
        dst[0] = pk2(v0, v1); dst[1] = pk2(v2, v3); dst[2] = pk2(v4, v5);
      }
    }
    __syncthreads();

    // ======== V3 (one 192x192x192 GEMM) + epi: mask1, W1^T -> sGZ =======
    {
      f4v acc[3][3] = {{{0,0,0,0},{0,0,0,0},{0,0,0,0}},
                       {{0,0,0,0},{0,0,0,0},{0,0,0,0}},
                       {{0,0,0,0},{0,0,0,0},{0,0,0,0}}};
      #pragma unroll 2
      for (int kk = 0; kk < 6; ++kk) {
        int jo = kk * 32 + lq * 8;
        s8v A[3], B[3];
        #pragma unroll
        for (int p = 0; p < 3; ++p)
          A[p] = *(const s8v*)(w2tl + ((mtg + p) * 16 + lm) * HID + jo);
        #pragma unroll
        for (int q = 0; q < 3; ++q)
          B[q] = *(const s8v*)&sGb[((ntg + q) * 16 + lm) * EST + jo];
        #pragma unroll
        for (int p = 0; p < 3; ++p)
          #pragma unroll
          for (int q = 0; q < 3; ++q)
            acc[p][q] = MFMA16(A[p], B[q], acc[p][q]);
      }
      float pz[3][6];
      #pragma unroll
      for (int q = 0; q < 3; ++q)
        #pragma unroll
        for (int i = 0; i < 6; ++i) pz[q][i] = 0.f;
      #pragma unroll
      for (int p = 0; p < 3; ++p) {
        int kb = (mtg + p) * 16 + lq * 4;
        float w1v[4][6];
        #pragma unroll
        for (int rg = 0; rg < 4; ++rg) {        // quad-broadcast LDS reads
          uint4 wr = *(const uint4*)(smraw + OB_W1 + (kb + rg) * 16);
          w1v[rg][0] = blo(wr.x); w1v[rg][1] = bhi(wr.x);
          w1v[rg][2] = blo(wr.y); w1v[rg][3] = bhi(wr.y);
          w1v[rg][4] = blo(wr.z); w1v[rg][5] = bhi(wr.z);
        }
        #pragma unroll
        for (int q = 0; q < 3; ++q) {
          int eq = (((ntg + q) & 1) << 4) + lm;  // col & 31
          const unsigned* mp = (const unsigned*)&sH1b[eq * EST + kb];
          unsigned mm0 = mp[0], mm1 = mp[1];
          unsigned short hb[4] = {
            (unsigned short)(mm0 & 0xffff), (unsigned short)(mm0 >> 16),
            (unsigned short)(mm1 & 0xffff), (unsigned short)(mm1 >> 16)};
          #pragma unroll
          for (int rg = 0; rg < 4; ++rg) {
            float val = hb[rg] ? acc[p][q][rg] : 0.f;
            pz[q][0] = fmaf(w1v[rg][0], val, pz[q][0]);
            pz[q][1] = fmaf(w1v[rg][1], val, pz[q][1]);
            pz[q][2] = fmaf(w1v[rg][2], val, pz[q][2]);
            pz[q][3] = fmaf(w1v[rg][3], val, pz[q][3]);
            pz[q][4] = fmaf(w1v[rg][4], val, pz[q][4]);
            pz[q][5] = fmaf(w1v[rg][5], val, pz[q][5]);
          }
        }
      }
      #pragma unroll
      for (int q = 0; q < 3; ++q)
        #pragma unroll
        for (int i = 0; i < 6; ++i) {
          float v = pz[q][i];
          v += __shfl_xor(v, 16);
          v += __shfl_xor(v, 32);
          if (lane < 16) atomicAdd(&sGZ[i * 192 + (ntg + q) * 16 + lane], v);
        }
    }
    __syncthreads();

    // ======== V5 (all rows): cotangent update; re-zero sGZ ==============
    for (int idx = tid; idx < 1152; idx += 1024) {
      int i   = idx / 192;           // 0..5
      int rem = idx - i * 192;       // col = r*32+e
      int r   = rem >> 5, e5 = rem & 31;
      float r1  = sR[(r * 12 + i) * EPB + e5];
      float r2o = sR[(r * 12 + 6 + i) * EPB + e5];
      float es  = sPRM[(2 * i + 1) * EPB + e5];
      sR[(r * 12 + i) * EPB + e5]     = r2o + sGZ[i * 192 + rem];
      sR[(r * 12 + 6 + i) * EPB + e5] = r1 * es;
      sGZ[i * 192 + rem] = 0.f;
    }
    __syncthreads();
  }

  // ---- epilogue ----
  if (tid < 192) {
    int i = tid >> 5;
    yz[(blk * EPB + e) * 12 + i]     = z_a;
    yz[(blk * EPB + e) * 12 + 6 + i] = z_b;
    atomicAdd(&sZQ[e], fmaf(z_a, z_a, z_b * z_b));
  }
  __syncthreads();
  if (tid < 32)
    out_lp[blk * EPB + tid] = sLD[tid] - 11.027262398456072f - 0.5f * sZQ[tid];

  float part = 0.f;
  for (int idx = tid; idx < 72 * EPB; idx += 1024) {
    int rt = idx >> 5, ee = idx & 31;
    float v = sR[idx];
    jp[(blk * EPB + ee) * 72 + rt] = v;
    part = fmaf(v, v, part);
  }
  #pragma unroll
  for (int off = 32; off > 0; off >>= 1) part += __shfl_down(part, off, 64);
  if ((tid & 63) == 0) atomicAdd(&sRed[0], part);
  __syncthreads();
  if (tid == 0) atomicAdd(ws_sum, sRed[0]);
}

// ---------------------------------------------------------------------
// kl_kernel: one thread per element (unchanged from R3..R7 PASS).
__global__ __launch_bounds__(256) void kl_kernel(
    const float* __restrict__ zin, const float* __restrict__ jpin,
    const float* __restrict__ Wsym, const float* __restrict__ lvd,
    const float* __restrict__ ws_sum, float* __restrict__ out_kl) {
  int elem = blockIdx.x * 256 + threadIdx.x;
  float z[12];
  #pragma unroll
  for (int i = 0; i < 12; ++i) z[i] = zin[elem * 12 + i];
  float scale = 1.0f / sqrtf(ws_sum[0]);
  float Jp[6][12];
  #pragma unroll
  for (int n = 0; n < 6; ++n)
    #pragma unroll
    for (int j = 0; j < 12; ++j)
      Jp[n][j] = jpin[elem * 72 + n * 12 + j] * scale;

  float Sq[78];
  #pragma unroll
  for (int i = 0; i < 78; ++i) Sq[i] = 0.f;
  float tq = 0.f, tpq = 0.f;

  for (int m = 0; m < NBASE; ++m) {
    const float* Wm = Wsym + m * 144;
    float jq[12];
    #pragma unroll
    for (int j = 0; j < 12; ++j) {
      float acc = 0.f;
      #pragma unroll
      for (int i = 0; i < 12; ++i)
        acc = fmaf(Wm[j * 12 + i] - Wm[i * 12 + j], z[i], acc);
      jq[j] = acc;
    }
    #pragma unroll
    for (int i = 0; i < 12; ++i) {
      tq = fmaf(jq[i], jq[i], tq);
      #pragma unroll
      for (int j = 0; j <= i; ++j)
        Sq[i * (i + 1) / 2 + j] = fmaf(jq[i], jq[j], Sq[i * (i + 1) / 2 + j]);
    }
    #pragma unroll
    for (int n = 0; n < 6; ++n) {
      float d = 0.f;
      #pragma unroll
      for (int j = 0; j < 12; ++j) d = fmaf(Jp[n][j], jq[j], d);
      tpq = fmaf(d, d, tpq);
    }
  }

  float Dv[12], Db[12];
  #pragma unroll
  for (int j = 0; j < 12; ++j) Dv[j] = expf(-lvd[j]);

  float mh = 0.f;
  #pragma unroll
  for (int i = 0; i < 12; ++i) mh += Sq[i * (i + 1) / 2 + i] + Dv[i];
  float norm_H = fmaxf(mh * (1.f / 12.f), 1e-6f);
  #pragma unroll
  for (int i = 0; i < 12; ++i) Sq[i * (i + 1) / 2 + i] += Dv[i] + 1e-3f * norm_H;
  float sumDb = 0.f;
  #pragma unroll
  for (int j = 0; j < 12; ++j) { Db[j] = Dv[j] + 1e-3f * norm_H; sumDb += Db[j]; }

  float M[21];
  #pragma unroll
  for (int n = 0; n < 6; ++n)
    #pragma unroll
    for (int mm = 0; mm <= n; ++mm) {
      float acc = 0.f;
      #pragma unroll
      for (int j = 0; j < 12; ++j) acc = fmaf(Jp[n][j], Jp[mm][j], acc);
      M[n * (n + 1) / 2 + mm] = acc;
    }
  float md = 0.f;
  #pragma unroll
  for (int i = 0; i < 6; ++i) md += M[i * (i + 1) / 2 + i];
  float norm_M = fmaxf(md * (1.f / 6.f) + EPSP, 1e-6f);
  #pragma unroll
  for (int i = 0; i < 6; ++i) M[i * (i + 1) / 2 + i] += EPSP + 1e-3f * norm_M;

  float trace_p = 0.f;
  #pragma unroll
  for (int n = 0; n < 6; ++n)
    #pragma unroll
    for (int j = 0; j < 12; ++j)
      trace_p = fmaf(Jp[n][j] * Jp[n][j], Db[j], trace_p);

  float trace = (EPSP + 1e-3f * norm_M) * (sumDb + tq) + trace_p + tpq;

  float ldM = 0.f;
  #pragma unroll
  for (int jc = 0; jc < 6; ++jc) {
    float d = M[jc * (jc + 1) / 2 + jc];
    #pragma unroll
    for (int k = 0; k < jc; ++k) d -= M[jc * (jc + 1) / 2 + k] * M[jc * (jc + 1) / 2 + k];
    d = sqrtf(d);
    ldM += logf(d);
    float di = 1.f / d;
    M[jc * (jc + 1) / 2 + jc] = d;
    #pragma unroll
    for (int i2 = jc + 1; i2 < 6; ++i2) {
      float v = M[i2 * (i2 + 1) / 2 + jc];
      #pragma unroll
      for (int k = 0; k < jc; ++k) v -= M[i2 * (i2 + 1) / 2 + k] * M[jc * (jc + 1) / 2 + k];
      M[i2 * (i2 + 1) / 2 + jc] = v * di;
    }
  }

  float ldH = 0.f;
  #pragma unroll
  for (int jc = 0; jc < 12; ++jc) {
    float d = Sq[jc * (jc + 1) / 2 + jc];
    #pragma unroll
    for (int k = 0; k < jc; ++k) d -= Sq[jc * (jc + 1) / 2 + k] * Sq[jc * (jc + 1) / 2 + k];
    d = sqrtf(d);
    ldH += logf(d);
    float di = 1.f / d;
    Sq[jc * (jc + 1) / 2 + jc] = d;
    #pragma unroll
    for (int i2 = jc + 1; i2 < 12; ++i2) {
      float v = Sq[i2 * (i2 + 1) / 2 + jc];
      #pragma unroll
      for (int k = 0; k < jc; ++k) v -= Sq[i2 * (i2 + 1) / 2 + k] * Sq[jc * (jc + 1) / 2 + k];
      Sq[i2 * (i2 + 1) / 2 + jc] = v * di;
    }
  }

  float logdet_p = 2.f * ldM + 6.f * logf(EPSP);
  float logdet_q = 2.f * ldH;
  out_kl[elem] = 0.5f * (trace - (logdet_p + logdet_q) - 12.f);
}

// ---------------------------------------------------------------------
extern "C" void kernel_launch(void* const* d_in, const int* in_sizes, int n_in,
                              void* d_out, int out_size, void* d_ws, size_t ws_size,
                              hipStream_t stream) {
  (void)in_sizes; (void)n_in; (void)out_size; (void)ws_size;
  float* y    = (float*)d_in[0];   // consumed, then overwritten with z
  float* Jp   = (float*)d_in[1];   // consumed, then overwritten with pullback Jp
  const float* W1   = (const float*)d_in[2];
  const float* b1   = (const float*)d_in[3];
  const float* W2   = (const float*)d_in[4];
  const float* b2   = (const float*)d_in[5];
  const float* W3   = (const float*)d_in[6];
  const float* b3   = (const float*)d_in[7];
  const float* Wsym = (const float*)d_in[8];
  const float* lvd  = (const float*)d_in[9];
  float* out = (float*)d_out;      // fp32: [log_prob (B), kl (B)]

  float* ws_sum = (float*)d_ws;
  unsigned short* w2b = (unsigned short*)((char*)d_ws + 256);
  unsigned short* w2t = (unsigned short*)((char*)d_ws + 256 +
                                          NLAYER * HID * HID * 2);
  hipMemsetAsync(d_ws, 0, 4, stream);

  hipFuncSetAttribute((const void*)flow_kernel,
                      hipFuncAttributeMaxDynamicSharedMemorySize, SMEM_BYTES);

  prep_kernel<<<3456, 256, 0, stream>>>(W2, w2b, w2t);
  flow_kernel<<<BTOT / EPB, 1024, SMEM_BYTES, stream>>>(
      y, Jp, W1, b1, b2, W3, b3, w2b, w2t, ws_sum, out);
  kl_kernel<<<64, 256, 0, stream>>>(y, Jp, Wsym, lvd, ws_sum, out + BTOT);
}

// Round 9
// 1985.791 us; speedup vs baseline: 1.2347x; 1.2347x over previous
//
#include <hip/hip_runtime.h>
#include <hip/hip_bf16.h>
#include <math.h>

#define BTOT   16384
#define NLAYER 24
#define HID    192
#define NDIN   12
#define NBASE  66
#define EPSP   1e-3f
#define EPB    16        // elements per block -> grid 1024

// ---------------- LDS layout (bytes), 62,240 total, STATIC ------------
// Static __shared__ (not dynamic extern): R3-R7 used dynamic LDS via
// hipFuncAttributeMaxDynamicSharedMemorySize and occupancy pinned at
// 1 block/CU (24%) regardless of size (41-105 KB). Theory: the dynamic
// path pessimizes residency. 62,240 B < 64 KB static limit; 2 blocks =
// 124.5 KB <= 160 KB/CU.
#define EST 200          // j/k stride (shorts) for sH1b/sGb rows
#define OB_H1  0         // ushort[16*200]  6400 : h1 bf16 [e][k]
#define OB_G   6400      // ushort[96*200] 38400 : h2 (rows 0-15) then G [col][j]
#define OB_R   44800     // float[72*16]    4608 : cotangent rows [rt][e]
#define OB_W1  49408     // ushort[192*8]   3072 : W1 bf16 rows padded to 8
#define OB_W3  52480     // ushort[192*16]  6144 : W3 bf16 [j][t] rows padded 16
#define OB_PRM 58624     // float[12*16]     768 : prm sums; then tf@2i, es@2i+1
#define OB_GZ  59392     // float[6*96]     2304 : g_z1 sums [i][col] (atomics)
#define OB_Z1  61696     // float[6*16]      384 : z[6..12) for next F1
#define OB_LD  62080     // float[16]         64 : logdet acc
#define OB_ZQ  62144     // float[16]         64 : sum z^2
#define OB_RED 62208     // float[8]          32
#define SMEM_BYTES 62240

typedef __attribute__((ext_vector_type(8))) short s8v;
typedef __attribute__((ext_vector_type(4))) float f4v;
#define MFMA16(a,b,c) __builtin_amdgcn_mfma_f32_16x16x32_bf16(a,b,c,0,0,0)

__device__ __forceinline__ unsigned short f2bf(float f) {
  unsigned u = __builtin_bit_cast(unsigned, f);
  u += 0x7fffu + ((u >> 16) & 1u);          // RNE
  return (unsigned short)(u >> 16);
}
__device__ __forceinline__ float bf2f(unsigned short h) {
  unsigned u = ((unsigned)h) << 16;
  return __builtin_bit_cast(float, u);
}
__device__ __forceinline__ unsigned pk2(float a, float b) {
  return (unsigned)f2bf(a) | ((unsigned)f2bf(b) << 16);
}
__device__ __forceinline__ float blo(unsigned u) { return bf2f((unsigned short)(u & 0xffff)); }
__device__ __forceinline__ float bhi(unsigned u) { return bf2f((unsigned short)(u >> 16)); }

// ---------------------------------------------------------------------
// prep: W2 -> bf16 (orig layout) and bf16 transpose, into workspace.
__global__ void prep_kernel(const float* __restrict__ W2,
                            unsigned short* __restrict__ w2b,
                            unsigned short* __restrict__ w2t) {
  int idx = blockIdx.x * 256 + threadIdx.x;   // 884736 exact
  int l   = idx / (HID * HID);
  int rem = idx - l * HID * HID;
  int k   = rem / HID;
  int j   = rem - k * HID;
  w2b[idx] = f2bf(W2[idx]);                         // [l][j][k]
  w2t[idx] = f2bf(W2[l * HID * HID + j * HID + k]); // [l][k][j]
}

// ---------------------------------------------------------------------
// flow_kernel: block = 16 elements, 512 threads (8 waves), grid 1024.
// Identical to R7 (1,821 us, VGPR 92, no spill) except STATIC LDS.
// NO min-blocks in launch_bounds: VGPR caps turn load-hoisting into
// spill (R5 (512,4): 291MB scratch; R6 (512,2): 808MB; R8 1024thr: 818MB).
__global__ __launch_bounds__(512) void flow_kernel(
    float* __restrict__ yz, float* __restrict__ jp,
    const float* __restrict__ W1, const float* __restrict__ b1,
    const float* __restrict__ b2,
    const float* __restrict__ W3, const float* __restrict__ b3,
    const unsigned short* __restrict__ w2b,
    const unsigned short* __restrict__ w2t,
    float* __restrict__ ws_sum, float* __restrict__ out_lp) {
  __shared__ char smraw[SMEM_BYTES];
  unsigned short* sH1b = (unsigned short*)(smraw + OB_H1);
  unsigned short* sGb  = (unsigned short*)(smraw + OB_G);
  unsigned short* sW3  = (unsigned short*)(smraw + OB_W3);
  float* sR   = (float*)(smraw + OB_R);
  float* sPRM = (float*)(smraw + OB_PRM);
  float* sGZ  = (float*)(smraw + OB_GZ);
  float* sZ1  = (float*)(smraw + OB_Z1);
  float* sLD  = (float*)(smraw + OB_LD);
  float* sZQ  = (float*)(smraw + OB_ZQ);
  float* sRed = (float*)(smraw + OB_RED);

  const int tid  = threadIdx.x;
  const int lane = tid & 63;
  const int w    = __builtin_amdgcn_readfirstlane(tid >> 6);
  const int e    = tid & 15;                     // element (scalar phases)
  const int s6   = (tid >> 4) * 6;               // 6-wide j slab (F1/S2/V2)
  const int lm   = lane & 15, lq = lane >> 4;    // MFMA lane coords
  const int mtg  = (w & 3) * 3;                  // m-tile base {0,3,6,9}
  const int ntg  = (w >> 2) * 3;                 // n-tile base {0,3}
  const int blk  = blockIdx.x;

  // ---- init ----
  float z_a = 0.f, z_b = 0.f;     // z[i], z[6+i] held by tid<96 (i=tid>>4)
  if (tid < 96) {
    int i = tid >> 4;
    z_a = yz[(blk * EPB + e) * 12 + i];
    z_b = yz[(blk * EPB + e) * 12 + 6 + i];
    sZ1[i * EPB + e] = z_b;
  }
  if (tid < 16) { sLD[tid] = 0.f; sZQ[tid] = 0.f; }
  if (tid == 0) sRed[0] = 0.f;
  if (tid >= 128 && tid < 128 + 576) sGZ[tid - 128] = 0.f;
  for (int idx = tid; idx < 72 * EPB; idx += 512) {
    int rt = idx >> 4, ee = idx & 15;
    sR[idx] = jp[(blk * EPB + ee) * 72 + rt];
  }
  __syncthreads();

  for (int l = NLAYER - 1; l >= 0; --l) {
    const float* W1l = W1 + l * HID * 6;
    const float* b1l = b1 + l * HID;
    const float* b2l = b2 + l * HID;
    const float* W3l = W3 + l * NDIN * HID;
    const float* b3l = b3 + l * NDIN;
    const unsigned short* w2bl = w2b + l * HID * HID;
    const unsigned short* w2tl = w2t + l * HID * HID;

    // ======== F1 phase: stage W1/W3 bf16, zero sPRM, h1 = relu(W1 z1+b1) =
    if (tid < 192) {
      const float* wr = W1l + tid * 6;
      uint4 pk;
      pk.x = pk2(wr[0], wr[1]); pk.y = pk2(wr[2], wr[3]);
      pk.z = pk2(wr[4], wr[5]); pk.w = 0;
      *(uint4*)(smraw + OB_W1 + tid * 16) = pk;
      // W3 [j][t] bf16, t-pairs packed
      unsigned* wd = (unsigned*)&sW3[tid * 16];
      #pragma unroll
      for (int c = 0; c < 6; ++c)
        wd[c] = pk2(W3l[(2 * c) * HID + tid], W3l[(2 * c + 1) * HID + tid]);
      sPRM[tid] = 0.f;
    }
    {
      float z1v[6];
      #pragma unroll
      for (int i = 0; i < 6; ++i) z1v[i] = sZ1[i * EPB + e];
      #pragma unroll
      for (int jj = 0; jj < 6; ++jj) {
        int j = s6 + jj;
        float acc = b1l[j];
        #pragma unroll
        for (int i = 0; i < 6; ++i) acc = fmaf(W1l[j * 6 + i], z1v[i], acc);
        sH1b[e * EST + j] = f2bf(fmaxf(acc, 0.f));
      }
    }
    __syncthreads();

    // ======== S1: F2 via MFMA (waves 0-3): h2 = relu(W2 h1+b2) -> rows 0-15
    if (w < 4) {
      f4v acc3[3] = {{0,0,0,0},{0,0,0,0},{0,0,0,0}};
      #pragma unroll 2
      for (int kk = 0; kk < 6; ++kk) {
        int jo = kk * 32 + lq * 8;
        s8v B = *(const s8v*)&sH1b[lm * EST + jo];
        #pragma unroll
        for (int p = 0; p < 3; ++p) {
          s8v A = *(const s8v*)(w2bl + ((mtg + p) * 16 + lm) * HID + jo);
          acc3[p] = MFMA16(A, B, acc3[p]);
        }
      }
      #pragma unroll
      for (int p = 0; p < 3; ++p) {
        int jb2 = (mtg + p) * 16 + lq * 4;
        float h0 = fmaxf(acc3[p][0] + b2l[jb2],     0.f);
        float h1 = fmaxf(acc3[p][1] + b2l[jb2 + 1], 0.f);
        float h2 = fmaxf(acc3[p][2] + b2l[jb2 + 2], 0.f);
        float h3 = fmaxf(acc3[p][3] + b2l[jb2 + 3], 0.f);
        unsigned* dst = (unsigned*)sGb + ((lm * EST + jb2) >> 1);
        dst[0] = pk2(h0, h1);
        dst[1] = pk2(h2, h3);
      }
    }
    __syncthreads();

    // ======== S2: prm partials (fp32 W3 from global) + wave-reduce ======
    {
      const unsigned* hp = (const unsigned*)&sGb[e * EST + s6];
      unsigned h2d0 = hp[0], h2d1 = hp[1], h2d2 = hp[2];
      float h2v[6] = { blo(h2d0), bhi(h2d0), blo(h2d1),
                       bhi(h2d1), blo(h2d2), bhi(h2d2) };
      #pragma unroll
      for (int t = 0; t < 12; ++t) {
        const float* w3r = W3l + t * HID + s6;
        float pp = 0.f;
        #pragma unroll
        for (int jj = 0; jj < 6; ++jj) pp = fmaf(w3r[jj], h2v[jj], pp);
        pp += __shfl_xor(pp, 16);
        pp += __shfl_xor(pp, 32);
        if (lane < 16) atomicAdd(&sPRM[t * EPB + lane], pp);
      }
    }
    __syncthreads();

    // ======== U: coupling update; sPRM becomes tf@(2i), es@(2i+1) ========
    if (tid < 96) {
      int i = tid >> 4;
      float sh = b3l[2 * i]     + sPRM[(2 * i) * EPB + e];
      float sr = b3l[2 * i + 1] + sPRM[(2 * i + 1) * EPB + e];
      float s  = 2.f * tanhf(0.5f * sr);
      float es = expf(s), en = expf(-s);
      float tv = z_a - sh;
      z_a = z_b;
      z_b = tv * en;
      sZ1[i * EPB + e] = z_b;
      sPRM[(2 * i) * EPB + e]     = tv * (1.f - 0.25f * s * s);  // tf
      sPRM[(2 * i + 1) * EPB + e] = es;                          // es
      atomicAdd(&sLD[e], -s);
    }
    __syncthreads();

    // ======== V2 (all 6 rows): G[col=r*16+e][j] = mask2 .* (W3^T gp_r) ===
    {
      const unsigned* hp = (const unsigned*)&sGb[e * EST + s6];
      unsigned h2d0 = hp[0], h2d1 = hp[1], h2d2 = hp[2];
      float tf[6];
      #pragma unroll
      for (int i = 0; i < 6; ++i) tf[i] = sPRM[(2 * i) * EPB + e];
      // weff[jj][c] = W3[2c][s6+jj] + tf[c]*W3[2c+1][s6+jj]  (bf16 W3)
      float weff[6][6];
      #pragma unroll
      for (int jj = 0; jj < 6; ++jj) {
        const unsigned* wd = (const unsigned*)&sW3[(s6 + jj) * 16];
        #pragma unroll
        for (int c = 0; c < 6; ++c) {
          unsigned wv = wd[c];
          weff[jj][c] = fmaf(tf[c], bhi(wv), blo(wv));
        }
      }
      #pragma unroll
      for (int r = 0; r < 6; ++r) {
        float g[6] = {0.f, 0.f, 0.f, 0.f, 0.f, 0.f};
        #pragma unroll
        for (int c = 0; c < 6; ++c) {
          float r1 = sR[(r * 12 + c) * EPB + e];
          #pragma unroll
          for (int jj = 0; jj < 6; ++jj)
            g[jj] = fmaf(weff[jj][c], r1, g[jj]);
        }
        unsigned* dst = (unsigned*)sGb + (((r * 16 + e) * EST + s6) >> 1);
        float v0 = (h2d0 & 0xffffu) ? g[0] : 0.f;
        float v1 = (h2d0 >> 16)     ? g[1] : 0.f;
        float v2 = (h2d1 & 0xffffu) ? g[2] : 0.f;
        float v3 = (h2d1 >> 16)     ? g[3] : 0.f;
        float v4 = (h2d2 & 0xffffu) ? g[4] : 0.f;
        float v5 = (h2d2 >> 16)     ? g[5] : 0.f;
        dst[0] = pk2(v0, v1); dst[1] = pk2(v2, v3); dst[2] = pk2(v4, v5);
      }
    }
    __syncthreads();

    // ======== V3 (all rows, one GEMM): D[k][col] = W2^T G; epi -> sGZ ====
    {
      f4v acc[3][3] = {{{0,0,0,0},{0,0,0,0},{0,0,0,0}},
                       {{0,0,0,0},{0,0,0,0},{0,0,0,0}},
                       {{0,0,0,0},{0,0,0,0},{0,0,0,0}}};
      #pragma unroll 2
      for (int kk = 0; kk < 6; ++kk) {
        int jo = kk * 32 + lq * 8;
        s8v A[3], B[3];
        #pragma unroll
        for (int p = 0; p < 3; ++p)
          A[p] = *(const s8v*)(w2tl + ((mtg + p) * 16 + lm) * HID + jo);
        #pragma unroll
        for (int q = 0; q < 3; ++q)
          B[q] = *(const s8v*)&sGb[((ntg + q) * 16 + lm) * EST + jo];
        #pragma unroll
        for (int p = 0; p < 3; ++p)
          #pragma unroll
          for (int q = 0; q < 3; ++q)
            acc[p][q] = MFMA16(A[p], B[q], acc[p][q]);
      }
      // epilogue: mask1 (e=lm, q-independent) + W1^T, accumulate pz[q][i]
      float pz[3][6];
      #pragma unroll
      for (int q = 0; q < 3; ++q)
        #pragma unroll
        for (int i = 0; i < 6; ++i) pz[q][i] = 0.f;
      #pragma unroll
      for (int p = 0; p < 3; ++p) {
        int kb = (mtg + p) * 16 + lq * 4;
        const unsigned* mp = (const unsigned*)&sH1b[lm * EST + kb];
        unsigned mm0 = mp[0], mm1 = mp[1];
        unsigned short hb[4] = {
          (unsigned short)(mm0 & 0xffff), (unsigned short)(mm0 >> 16),
          (unsigned short)(mm1 & 0xffff), (unsigned short)(mm1 >> 16)};
        #pragma unroll
        for (int rg = 0; rg < 4; ++rg) {
          uint4 wr = *(const uint4*)(smraw + OB_W1 + (kb + rg) * 16);
          float w10 = blo(wr.x), w11 = bhi(wr.x), w12 = blo(wr.y);
          float w13 = bhi(wr.y), w14 = blo(wr.z), w15 = bhi(wr.z);
          #pragma unroll
          for (int q = 0; q < 3; ++q) {
            float val = hb[rg] ? acc[p][q][rg] : 0.f;
            pz[q][0] = fmaf(w10, val, pz[q][0]);
            pz[q][1] = fmaf(w11, val, pz[q][1]);
            pz[q][2] = fmaf(w12, val, pz[q][2]);
            pz[q][3] = fmaf(w13, val, pz[q][3]);
            pz[q][4] = fmaf(w14, val, pz[q][4]);
            pz[q][5] = fmaf(w15, val, pz[q][5]);
          }
        }
      }
      // wave-reduce over lq (xor 16/32), then one atomic per (q,i) from lm lanes
      #pragma unroll
      for (int q = 0; q < 3; ++q)
        #pragma unroll
        for (int i = 0; i < 6; ++i) {
          float v = pz[q][i];
          v += __shfl_xor(v, 16);
          v += __shfl_xor(v, 32);
          if (lane < 16) atomicAdd(&sGZ[i * 96 + (ntg + q) * 16 + lane], v);
        }
    }
    __syncthreads();

    // ======== V5 (all rows): cotangent update; re-zero sGZ ==============
    for (int idx = tid; idx < 576; idx += 512) {
      int i   = idx / 96;            // 0..5
      int rem = idx - i * 96;        // r*16+e
      int r   = rem >> 4, e5 = rem & 15;
      float r1  = sR[(r * 12 + i) * EPB + e5];
      float r2o = sR[(r * 12 + 6 + i) * EPB + e5];
      float es  = sPRM[(2 * i + 1) * EPB + e5];
      sR[(r * 12 + i) * EPB + e5]     = r2o + sGZ[i * 96 + rem];
      sR[(r * 12 + 6 + i) * EPB + e5] = r1 * es;
      sGZ[i * 96 + rem] = 0.f;
    }
    __syncthreads();
  }

  // ---- epilogue ----
  if (tid < 96) {
    int i = tid >> 4;
    yz[(blk * EPB + e) * 12 + i]     = z_a;
    yz[(blk * EPB + e) * 12 + 6 + i] = z_b;
    atomicAdd(&sZQ[e], fmaf(z_a, z_a, z_b * z_b));
  }
  __syncthreads();
  if (tid < 16)
    out_lp[blk * EPB + tid] = sLD[tid] - 11.027262398456072f - 0.5f * sZQ[tid];

  float part = 0.f;
  for (int idx = tid; idx < 72 * EPB; idx += 512) {
    int rt = idx >> 4, ee = idx & 15;
    float v = sR[idx];
    jp[(blk * EPB + ee) * 72 + rt] = v;
    part = fmaf(v, v, part);
  }
  #pragma unroll
  for (int off = 32; off > 0; off >>= 1) part += __shfl_down(part, off, 64);
  if ((tid & 63) == 0) atomicAdd(&sRed[0], part);
  __syncthreads();
  if (tid == 0) atomicAdd(ws_sum, sRed[0]);
}

// ---------------------------------------------------------------------
// kl_kernel: one thread per element (unchanged from R3..R8 PASS).
__global__ __launch_bounds__(256) void kl_kernel(
    const float* __restrict__ zin, const float* __restrict__ jpin,
    const float* __restrict__ Wsym, const float* __restrict__ lvd,
    const float* __restrict__ ws_sum, float* __restrict__ out_kl) {
  int elem = blockIdx.x * 256 + threadIdx.x;
  float z[12];
  #pragma unroll
  for (int i = 0; i < 12; ++i) z[i] = zin[elem * 12 + i];
  float scale = 1.0f / sqrtf(ws_sum[0]);
  float Jp[6][12];
  #pragma unroll
  for (int n = 0; n < 6; ++n)
    #pragma unroll
    for (int j = 0; j < 12; ++j)
      Jp[n][j] = jpin[elem * 72 + n * 12 + j] * scale;

  float Sq[78];
  #pragma unroll
  for (int i = 0; i < 78; ++i) Sq[i] = 0.f;
  float tq = 0.f, tpq = 0.f;

  for (int m = 0; m < NBASE; ++m) {
    const float* Wm = Wsym + m * 144;
    float jq[12];
    #pragma unroll
    for (int j = 0; j < 12; ++j) {
      float acc = 0.f;
      #pragma unroll
      for (int i = 0; i < 12; ++i)
        acc = fmaf(Wm[j * 12 + i] - Wm[i * 12 + j], z[i], acc);
      jq[j] = acc;
    }
    #pragma unroll
    for (int i = 0; i < 12; ++i) {
      tq = fmaf(jq[i], jq[i], tq);
      #pragma unroll
      for (int j = 0; j <= i; ++j)
        Sq[i * (i + 1) / 2 + j] = fmaf(jq[i], jq[j], Sq[i * (i + 1) / 2 + j]);
    }
    #pragma unroll
    for (int n = 0; n < 6; ++n) {
      float d = 0.f;
      #pragma unroll
      for (int j = 0; j < 12; ++j) d = fmaf(Jp[n][j], jq[j], d);
      tpq = fmaf(d, d, tpq);
    }
  }

  float Dv[12], Db[12];
  #pragma unroll
  for (int j = 0; j < 12; ++j) Dv[j] = expf(-lvd[j]);

  float mh = 0.f;
  #pragma unroll
  for (int i = 0; i < 12; ++i) mh += Sq[i * (i + 1) / 2 + i] + Dv[i];
  float norm_H = fmaxf(mh * (1.f / 12.f), 1e-6f);
  #pragma unroll
  for (int i = 0; i < 12; ++i) Sq[i * (i + 1) / 2 + i] += Dv[i] + 1e-3f * norm_H;
  float sumDb = 0.f;
  #pragma unroll
  for (int j = 0; j < 12; ++j) { Db[j] = Dv[j] + 1e-3f * norm_H; sumDb += Db[j]; }

  float M[21];
  #pragma unroll
  for (int n = 0; n < 6; ++n)
    #pragma unroll
    for (int mm = 0; mm <= n; ++mm) {
      float acc = 0.f;
      #pragma unroll
      for (int j = 0; j < 12; ++j) acc = fmaf(Jp[n][j], Jp[mm][j], acc);
      M[n * (n + 1) / 2 + mm] = acc;
    }
  float md = 0.f;
  #pragma unroll
  for (int i = 0; i < 6; ++i) md += M[i * (i + 1) / 2 + i];
  float norm_M = fmaxf(md * (1.f / 6.f) + EPSP, 1e-6f);
  #pragma unroll
  for (int i = 0; i < 6; ++i) M[i * (i + 1) / 2 + i] += EPSP + 1e-3f * norm_M;

  float trace_p = 0.f;
  #pragma unroll
  for (int n = 0; n < 6; ++n)
    #pragma unroll
    for (int j = 0; j < 12; ++j)
      trace_p = fmaf(Jp[n][j] * Jp[n][j], Db[j], trace_p);

  float trace = (EPSP + 1e-3f * norm_M) * (sumDb + tq) + trace_p + tpq;

  float ldM = 0.f;
  #pragma unroll
  for (int jc = 0; jc < 6; ++jc) {
    float d = M[jc * (jc + 1) / 2 + jc];
    #pragma unroll
    for (int k = 0; k < jc; ++k) d -= M[jc * (jc + 1) / 2 + k] * M[jc * (jc + 1) / 2 + k];
    d = sqrtf(d);
    ldM += logf(d);
    float di = 1.f / d;
    M[jc * (jc + 1) / 2 + jc] = d;
    #pragma unroll
    for (int i2 = jc + 1; i2 < 6; ++i2) {
      float v = M[i2 * (i2 + 1) / 2 + jc];
      #pragma unroll
      for (int k = 0; k < jc; ++k) v -= M[i2 * (i2 + 1) / 2 + k] * M[jc * (jc + 1) / 2 + k];
      M[i2 * (i2 + 1) / 2 + jc] = v * di;
    }
  }

  float ldH = 0.f;
  #pragma unroll
  for (int jc = 0; jc < 12; ++jc) {
    float d = Sq[jc * (jc + 1) / 2 + jc];
    #pragma unroll
    for (int k = 0; k < jc; ++k) d -= Sq[jc * (jc + 1) / 2 + k] * Sq[jc * (jc + 1) / 2 + k];
    d = sqrtf(d);
    ldH += logf(d);
    float di = 1.f / d;
    Sq[jc * (jc + 1) / 2 + jc] = d;
    #pragma unroll
    for (int i2 = jc + 1; i2 < 12; ++i2) {
      float v = Sq[i2 * (i2 + 1) / 2 + jc];
      #pragma unroll
      for (int k = 0; k < jc; ++k) v -= Sq[i2 * (i2 + 1) / 2 + k] * Sq[jc * (jc + 1) / 2 + k];
      Sq[i2 * (i2 + 1) / 2 + jc] = v * di;
    }
  }

  float logdet_p = 2.f * ldM + 6.f * logf(EPSP);
  float logdet_q = 2.f * ldH;
  out_kl[elem] = 0.5f * (trace - (logdet_p + logdet_q) - 12.f);
}

// ---------------------------------------------------------------------
extern "C" void kernel_launch(void* const* d_in, const int* in_sizes, int n_in,
                              void* d_out, int out_size, void* d_ws, size_t ws_size,
                              hipStream_t stream) {
  (void)in_sizes; (void)n_in; (void)out_size; (void)ws_size;
  float* y    = (float*)d_in[0];   // consumed, then overwritten with z
  float* Jp   = (float*)d_in[1];   // consumed, then overwritten with pullback Jp
  const float* W1   = (const float*)d_in[2];
  const float* b1   = (const float*)d_in[3];
  const float* W2   = (const float*)d_in[4];
  const float* b2   = (const float*)d_in[5];
  const float* W3   = (const float*)d_in[6];
  const float* b3   = (const float*)d_in[7];
  const float* Wsym = (const float*)d_in[8];
  const float* lvd  = (const float*)d_in[9];
  float* out = (float*)d_out;      // fp32: [log_prob (B), kl (B)]

  float* ws_sum = (float*)d_ws;
  unsigned short* w2b = (unsigned short*)((char*)d_ws + 256);
  unsigned short* w2t = (unsigned short*)((char*)d_ws + 256 +
                                          NLAYER * HID * HID * 2);
  hipMemsetAsync(d_ws, 0, 4, stream);

  prep_kernel<<<3456, 256, 0, stream>>>(W2, w2b, w2t);
  flow_kernel<<<BTOT / EPB, 512, 0, stream>>>(
      y, Jp, W1, b1, b2, W3, b3, w2b, w2t, ws_sum, out);
  kl_kernel<<<64, 256, 0, stream>>>(y, Jp, Wsym, lvd, ws_sum, out + BTOT);
}

// Round 10
// 1982.802 us; speedup vs baseline: 1.2366x; 1.0015x over previous
//
#include <hip/hip_runtime.h>
#include <hip/hip_bf16.h>
#include <math.h>

#define BTOT   16384
#define NLAYER 24
#define HID    192
#define NDIN   12
#define NBASE  66
#define EPSP   1e-3f
#define EPB    16        // elements per block -> grid 1024

// ---------------- LDS layout (bytes), 62,240 total, static ------------
#define EST 200          // j/k stride (shorts) for sH1b/sGb rows
#define OB_H1  0         // ushort[16*200]  6400 : h1 bf16 [e][k]
#define OB_G   6400      // ushort[96*200] 38400 : h2 (rows 0-15) then G [col][j]
#define OB_R   44800     // float[72*16]    4608 : cotangent rows [rt][e]
#define OB_W1  49408     // ushort[192*8]   3072 : W1 bf16 rows padded to 8
#define OB_W3  52480     // ushort[192*16]  6144 : W3 bf16 [j][t] rows padded 16
#define OB_PRM 58624     // float[12*16]     768 : prm sums; then tf@2i, es@2i+1
#define OB_GZ  59392     // float[6*96]     2304 : g_z1 sums [i][col] (atomics)
#define OB_Z1  61696     // float[6*16]      384 : z[6..12) for next F1
#define OB_LD  62080     // float[16]         64 : logdet acc
#define OB_ZQ  62144     // float[16]         64 : sum z^2
#define OB_RED 62208     // float[8]          32
#define SMEM_BYTES 62240

typedef __attribute__((ext_vector_type(8))) short s8v;
typedef __attribute__((ext_vector_type(4))) float f4v;
#define MFMA16(a,b,c) __builtin_amdgcn_mfma_f32_16x16x32_bf16(a,b,c,0,0,0)

__device__ __forceinline__ unsigned short f2bf(float f) {
  unsigned u = __builtin_bit_cast(unsigned, f);
  u += 0x7fffu + ((u >> 16) & 1u);          // RNE
  return (unsigned short)(u >> 16);
}
__device__ __forceinline__ float bf2f(unsigned short h) {
  unsigned u = ((unsigned)h) << 16;
  return __builtin_bit_cast(float, u);
}
__device__ __forceinline__ unsigned pk2(float a, float b) {
  return (unsigned)f2bf(a) | ((unsigned)f2bf(b) << 16);
}
__device__ __forceinline__ float blo(unsigned u) { return bf2f((unsigned short)(u & 0xffff)); }
__device__ __forceinline__ float bhi(unsigned u) { return bf2f((unsigned short)(u >> 16)); }

// ---------------------------------------------------------------------
// prep: W2 -> bf16 (orig layout) and bf16 transpose, into workspace.
__global__ void prep_kernel(const float* __restrict__ W2,
                            unsigned short* __restrict__ w2b,
                            unsigned short* __restrict__ w2t) {
  int idx = blockIdx.x * 256 + threadIdx.x;   // 884736 exact
  int l   = idx / (HID * HID);
  int rem = idx - l * HID * HID;
  int k   = rem / HID;
  int j   = rem - k * HID;
  w2b[idx] = f2bf(W2[idx]);                         // [l][j][k]
  w2t[idx] = f2bf(W2[l * HID * HID + j * HID + k]); // [l][k][j]
}

// ---------------------------------------------------------------------
// flow_kernel: block = 16 elements, 512 threads (8 waves), grid 1024.
// R9 structure. Residency theory: 2 blocks/CU need 4 waves/SIMD ->
// combined VGPR+AGPR <= 128/wave. R9: 92 arch VGPR (+36 AGPR acc) = 136
// rounds past 128 -> only 3 waves/SIMD -> 2nd block never fits. Shave:
// kk-loops unroll 1 (halve in-flight frags) + amdgpu_waves_per_eu(4)
// (the correct cap knob; launch_bounds minBlocks slammed cap to 64
// and spilled 291-818MB in R5/R6/R8).
__global__ __launch_bounds__(512)
__attribute__((amdgpu_waves_per_eu(4)))
void flow_kernel(
    float* __restrict__ yz, float* __restrict__ jp,
    const float* __restrict__ W1, const float* __restrict__ b1,
    const float* __restrict__ b2,
    const float* __restrict__ W3, const float* __restrict__ b3,
    const unsigned short* __restrict__ w2b,
    const unsigned short* __restrict__ w2t,
    float* __restrict__ ws_sum, float* __restrict__ out_lp) {
  __shared__ char smraw[SMEM_BYTES];
  unsigned short* sH1b = (unsigned short*)(smraw + OB_H1);
  unsigned short* sGb  = (unsigned short*)(smraw + OB_G);
  unsigned short* sW3  = (unsigned short*)(smraw + OB_W3);
  float* sR   = (float*)(smraw + OB_R);
  float* sPRM = (float*)(smraw + OB_PRM);
  float* sGZ  = (float*)(smraw + OB_GZ);
  float* sZ1  = (float*)(smraw + OB_Z1);
  float* sLD  = (float*)(smraw + OB_LD);
  float* sZQ  = (float*)(smraw + OB_ZQ);
  float* sRed = (float*)(smraw + OB_RED);

  const int tid  = threadIdx.x;
  const int lane = tid & 63;
  const int w    = __builtin_amdgcn_readfirstlane(tid >> 6);
  const int e    = tid & 15;                     // element (scalar phases)
  const int s6   = (tid >> 4) * 6;               // 6-wide j slab (F1/S2/V2)
  const int lm   = lane & 15, lq = lane >> 4;    // MFMA lane coords
  const int mtg  = (w & 3) * 3;                  // m-tile base {0,3,6,9}
  const int ntg  = (w >> 2) * 3;                 // n-tile base {0,3}
  const int blk  = blockIdx.x;

  // ---- init ----
  float z_a = 0.f, z_b = 0.f;     // z[i], z[6+i] held by tid<96 (i=tid>>4)
  if (tid < 96) {
    int i = tid >> 4;
    z_a = yz[(blk * EPB + e) * 12 + i];
    z_b = yz[(blk * EPB + e) * 12 + 6 + i];
    sZ1[i * EPB + e] = z_b;
  }
  if (tid < 16) { sLD[tid] = 0.f; sZQ[tid] = 0.f; }
  if (tid == 0) sRed[0] = 0.f;
  if (tid >= 128 && tid < 128 + 576) sGZ[tid - 128] = 0.f;
  for (int idx = tid; idx < 72 * EPB; idx += 512) {
    int rt = idx >> 4, ee = idx & 15;
    sR[idx] = jp[(blk * EPB + ee) * 72 + rt];
  }
  __syncthreads();

  for (int l = NLAYER - 1; l >= 0; --l) {
    const float* W1l = W1 + l * HID * 6;
    const float* b1l = b1 + l * HID;
    const float* b2l = b2 + l * HID;
    const float* W3l = W3 + l * NDIN * HID;
    const float* b3l = b3 + l * NDIN;
    const unsigned short* w2bl = w2b + l * HID * HID;
    const unsigned short* w2tl = w2t + l * HID * HID;

    // ======== F1 phase: stage W1/W3 bf16, zero sPRM, h1 = relu(W1 z1+b1) =
    if (tid < 192) {
      const float* wr = W1l + tid * 6;
      uint4 pk;
      pk.x = pk2(wr[0], wr[1]); pk.y = pk2(wr[2], wr[3]);
      pk.z = pk2(wr[4], wr[5]); pk.w = 0;
      *(uint4*)(smraw + OB_W1 + tid * 16) = pk;
      // W3 [j][t] bf16, t-pairs packed
      unsigned* wd = (unsigned*)&sW3[tid * 16];
      #pragma unroll
      for (int c = 0; c < 6; ++c)
        wd[c] = pk2(W3l[(2 * c) * HID + tid], W3l[(2 * c + 1) * HID + tid]);
      sPRM[tid] = 0.f;
    }
    {
      float z1v[6];
      #pragma unroll
      for (int i = 0; i < 6; ++i) z1v[i] = sZ1[i * EPB + e];
      #pragma unroll
      for (int jj = 0; jj < 6; ++jj) {
        int j = s6 + jj;
        float acc = b1l[j];
        #pragma unroll
        for (int i = 0; i < 6; ++i) acc = fmaf(W1l[j * 6 + i], z1v[i], acc);
        sH1b[e * EST + j] = f2bf(fmaxf(acc, 0.f));
      }
    }
    __syncthreads();

    // ======== S1: F2 via MFMA (waves 0-3): h2 = relu(W2 h1+b2) -> rows 0-15
    if (w < 4) {
      f4v acc3[3] = {{0,0,0,0},{0,0,0,0},{0,0,0,0}};
      #pragma unroll 1
      for (int kk = 0; kk < 6; ++kk) {
        int jo = kk * 32 + lq * 8;
        s8v B = *(const s8v*)&sH1b[lm * EST + jo];
        #pragma unroll
        for (int p = 0; p < 3; ++p) {
          s8v A = *(const s8v*)(w2bl + ((mtg + p) * 16 + lm) * HID + jo);
          acc3[p] = MFMA16(A, B, acc3[p]);
        }
      }
      #pragma unroll
      for (int p = 0; p < 3; ++p) {
        int jb2 = (mtg + p) * 16 + lq * 4;
        float h0 = fmaxf(acc3[p][0] + b2l[jb2],     0.f);
        float h1 = fmaxf(acc3[p][1] + b2l[jb2 + 1], 0.f);
        float h2 = fmaxf(acc3[p][2] + b2l[jb2 + 2], 0.f);
        float h3 = fmaxf(acc3[p][3] + b2l[jb2 + 3], 0.f);
        unsigned* dst = (unsigned*)sGb + ((lm * EST + jb2) >> 1);
        dst[0] = pk2(h0, h1);
        dst[1] = pk2(h2, h3);
      }
    }
    __syncthreads();

    // ======== S2: prm partials (fp32 W3 from global) + wave-reduce ======
    {
      const unsigned* hp = (const unsigned*)&sGb[e * EST + s6];
      unsigned h2d0 = hp[0], h2d1 = hp[1], h2d2 = hp[2];
      float h2v[6] = { blo(h2d0), bhi(h2d0), blo(h2d1),
                       bhi(h2d1), blo(h2d2), bhi(h2d2) };
      #pragma unroll
      for (int t = 0; t < 12; ++t) {
        const float* w3r = W3l + t * HID + s6;
        float pp = 0.f;
        #pragma unroll
        for (int jj = 0; jj < 6; ++jj) pp = fmaf(w3r[jj], h2v[jj], pp);
        pp += __shfl_xor(pp, 16);
        pp += __shfl_xor(pp, 32);
        if (lane < 16) atomicAdd(&sPRM[t * EPB + lane], pp);
      }
    }
    __syncthreads();

    // ======== U: coupling update; sPRM becomes tf@(2i), es@(2i+1) ========
    if (tid < 96) {
      int i = tid >> 4;
      float sh = b3l[2 * i]     + sPRM[(2 * i) * EPB + e];
      float sr = b3l[2 * i + 1] + sPRM[(2 * i + 1) * EPB + e];
      float s  = 2.f * tanhf(0.5f * sr);
      float es = expf(s), en = expf(-s);
      float tv = z_a - sh;
      z_a = z_b;
      z_b = tv * en;
      sZ1[i * EPB + e] = z_b;
      sPRM[(2 * i) * EPB + e]     = tv * (1.f - 0.25f * s * s);  // tf
      sPRM[(2 * i + 1) * EPB + e] = es;                          // es
      atomicAdd(&sLD[e], -s);
    }
    __syncthreads();

    // ======== V2 (all 6 rows): G[col=r*16+e][j] = mask2 .* (W3^T gp_r) ===
    {
      const unsigned* hp = (const unsigned*)&sGb[e * EST + s6];
      unsigned h2d0 = hp[0], h2d1 = hp[1], h2d2 = hp[2];
      float tf[6];
      #pragma unroll
      for (int i = 0; i < 6; ++i) tf[i] = sPRM[(2 * i) * EPB + e];
      // weff[jj][c] = W3[2c][s6+jj] + tf[c]*W3[2c+1][s6+jj]  (bf16 W3)
      float weff[6][6];
      #pragma unroll
      for (int jj = 0; jj < 6; ++jj) {
        const unsigned* wd = (const unsigned*)&sW3[(s6 + jj) * 16];
        #pragma unroll
        for (int c = 0; c < 6; ++c) {
          unsigned wv = wd[c];
          weff[jj][c] = fmaf(tf[c], bhi(wv), blo(wv));
        }
      }
      #pragma unroll
      for (int r = 0; r < 6; ++r) {
        float g[6] = {0.f, 0.f, 0.f, 0.f, 0.f, 0.f};
        #pragma unroll
        for (int c = 0; c < 6; ++c) {
          float r1 = sR[(r * 12 + c) * EPB + e];
          #pragma unroll
          for (int jj = 0; jj < 6; ++jj)
            g[jj] = fmaf(weff[jj][c], r1, g[jj]);
        }
        unsigned* dst = (unsigned*)sGb + (((r * 16 + e) * EST + s6) >> 1);
        float v0 = (h2d0 & 0xffffu) ? g[0] : 0.f;
        float v1 = (h2d0 >> 16)     ? g[1] : 0.f;
        float v2 = (h2d1 & 0xffffu) ? g[2] : 0.f;
        float v3 = (h2d1 >> 16)     ? g[3] : 0.f;
        float v4 = (h2d2 & 0xffffu) ? g[4] : 0.f;
        float v5 = (h2d2 >> 16)     ? g[5] : 0.f;
        dst[0] = pk2(v0, v1); dst[1] = pk2(v2, v3); dst[2] = pk2(v4, v5);
      }
    }
    __syncthreads();

    // ======== V3 (all rows, one GEMM): D[k][col] = W2^T G; epi -> sGZ ====
    {
      f4v acc[3][3] = {{{0,0,0,0},{0,0,0,0},{0,0,0,0}},
                       {{0,0,0,0},{0,0,0,0},{0,0,0,0}},
                       {{0,0,0,0},{0,0,0,0},{0,0,0,0}}};
      #pragma unroll 1
      for (int kk = 0; kk < 6; ++kk) {
        int jo = kk * 32 + lq * 8;
        s8v A[3], B[3];
        #pragma unroll
        for (int p = 0; p < 3; ++p)
          A[p] = *(const s8v*)(w2tl + ((mtg + p) * 16 + lm) * HID + jo);
        #pragma unroll
        for (int q = 0; q < 3; ++q)
          B[q] = *(const s8v*)&sGb[((ntg + q) * 16 + lm) * EST + jo];
        #pragma unroll
        for (int p = 0; p < 3; ++p)
          #pragma unroll
          for (int q = 0; q < 3; ++q)
            acc[p][q] = MFMA16(A[p], B[q], acc[p][q]);
      }
      // epilogue: mask1 (e=lm, q-independent) + W1^T, accumulate pz[q][i]
      float pz[3][6];
      #pragma unroll
      for (int q = 0; q < 3; ++q)
        #pragma unroll
        for (int i = 0; i < 6; ++i) pz[q][i] = 0.f;
      #pragma unroll
      for (int p = 0; p < 3; ++p) {
        int kb = (mtg + p) * 16 + lq * 4;
        const unsigned* mp = (const unsigned*)&sH1b[lm * EST + kb];
        unsigned mm0 = mp[0], mm1 = mp[1];
        unsigned short hb[4] = {
          (unsigned short)(mm0 & 0xffff), (unsigned short)(mm0 >> 16),
          (unsigned short)(mm1 & 0xffff), (unsigned short)(mm1 >> 16)};
        #pragma unroll
        for (int rg = 0; rg < 4; ++rg) {
          uint4 wr = *(const uint4*)(smraw + OB_W1 + (kb + rg) * 16);
          float w10 = blo(wr.x), w11 = bhi(wr.x), w12 = blo(wr.y);
          float w13 = bhi(wr.y), w14 = blo(wr.z), w15 = bhi(wr.z);
          #pragma unroll
          for (int q = 0; q < 3; ++q) {
            float val = hb[rg] ? acc[p][q][rg] : 0.f;
            pz[q][0] = fmaf(w10, val, pz[q][0]);
            pz[q][1] = fmaf(w11, val, pz[q][1]);
            pz[q][2] = fmaf(w12, val, pz[q][2]);
            pz[q][3] = fmaf(w13, val, pz[q][3]);
            pz[q][4] = fmaf(w14, val, pz[q][4]);
            pz[q][5] = fmaf(w15, val, pz[q][5]);
          }
        }
      }
      // wave-reduce over lq (xor 16/32), then one atomic per (q,i) from lm lanes
      #pragma unroll
      for (int q = 0; q < 3; ++q)
        #pragma unroll
        for (int i = 0; i < 6; ++i) {
          float v = pz[q][i];
          v += __shfl_xor(v, 16);
          v += __shfl_xor(v, 32);
          if (lane < 16) atomicAdd(&sGZ[i * 96 + (ntg + q) * 16 + lane], v);
        }
    }
    __syncthreads();

    // ======== V5 (all rows): cotangent update; re-zero sGZ ==============
    for (int idx = tid; idx < 576; idx += 512) {
      int i   = idx / 96;            // 0..5
      int rem = idx - i * 96;        // r*16+e
      int r   = rem >> 4, e5 = rem & 15;
      float r1  = sR[(r * 12 + i) * EPB + e5];
      float r2o = sR[(r * 12 + 6 + i) * EPB + e5];
      float es  = sPRM[(2 * i + 1) * EPB + e5];
      sR[(r * 12 + i) * EPB + e5]     = r2o + sGZ[i * 96 + rem];
      sR[(r * 12 + 6 + i) * EPB + e5] = r1 * es;
      sGZ[i * 96 + rem] = 0.f;
    }
    __syncthreads();
  }

  // ---- epilogue ----
  if (tid < 96) {
    int i = tid >> 4;
    yz[(blk * EPB + e) * 12 + i]     = z_a;
    yz[(blk * EPB + e) * 12 + 6 + i] = z_b;
    atomicAdd(&sZQ[e], fmaf(z_a, z_a, z_b * z_b));
  }
  __syncthreads();
  if (tid < 16)
    out_lp[blk * EPB + tid] = sLD[tid] - 11.027262398456072f - 0.5f * sZQ[tid];

  float part = 0.f;
  for (int idx = tid; idx < 72 * EPB; idx += 512) {
    int rt = idx >> 4, ee = idx & 15;
    float v = sR[idx];
    jp[(blk * EPB + ee) * 72 + rt] = v;
    part = fmaf(v, v, part);
  }
  #pragma unroll
  for (int off = 32; off > 0; off >>= 1) part += __shfl_down(part, off, 64);
  if ((tid & 63) == 0) atomicAdd(&sRed[0], part);
  __syncthreads();
  if (tid == 0) atomicAdd(ws_sum, sRed[0]);
}

// ---------------------------------------------------------------------
// kl_kernel: one thread per element (unchanged from R3..R9 PASS).
__global__ __launch_bounds__(256) void kl_kernel(
    const float* __restrict__ zin, const float* __restrict__ jpin,
    const float* __restrict__ Wsym, const float* __restrict__ lvd,
    const float* __restrict__ ws_sum, float* __restrict__ out_kl) {
  int elem = blockIdx.x * 256 + threadIdx.x;
  float z[12];
  #pragma unroll
  for (int i = 0; i < 12; ++i) z[i] = zin[elem * 12 + i];
  float scale = 1.0f / sqrtf(ws_sum[0]);
  float Jp[6][12];
  #pragma unroll
  for (int n = 0; n < 6; ++n)
    #pragma unroll
    for (int j = 0; j < 12; ++j)
      Jp[n][j] = jpin[elem * 72 + n * 12 + j] * scale;

  float Sq[78];
  #pragma unroll
  for (int i = 0; i < 78; ++i) Sq[i] = 0.f;
  float tq = 0.f, tpq = 0.f;

  for (int m = 0; m < NBASE; ++m) {
    const float* Wm = Wsym + m * 144;
    float jq[12];
    #pragma unroll
    for (int j = 0; j < 12; ++j) {
      float acc = 0.f;
      #pragma unroll
      for (int i = 0; i < 12; ++i)
        acc = fmaf(Wm[j * 12 + i] - Wm[i * 12 + j], z[i], acc);
      jq[j] = acc;
    }
    #pragma unroll
    for (int i = 0; i < 12; ++i) {
      tq = fmaf(jq[i], jq[i], tq);
      #pragma unroll
      for (int j = 0; j <= i; ++j)
        Sq[i * (i + 1) / 2 + j] = fmaf(jq[i], jq[j], Sq[i * (i + 1) / 2 + j]);
    }
    #pragma unroll
    for (int n = 0; n < 6; ++n) {
      float d = 0.f;
      #pragma unroll
      for (int j = 0; j < 12; ++j) d = fmaf(Jp[n][j], jq[j], d);
      tpq = fmaf(d, d, tpq);
    }
  }

  float Dv[12], Db[12];
  #pragma unroll
  for (int j = 0; j < 12; ++j) Dv[j] = expf(-lvd[j]);

  float mh = 0.f;
  #pragma unroll
  for (int i = 0; i < 12; ++i) mh += Sq[i * (i + 1) / 2 + i] + Dv[i];
  float norm_H = fmaxf(mh * (1.f / 12.f), 1e-6f);
  #pragma unroll
  for (int i = 0; i < 12; ++i) Sq[i * (i + 1) / 2 + i] += Dv[i] + 1e-3f * norm_H;
  float sumDb = 0.f;
  #pragma unroll
  for (int j = 0; j < 12; ++j) { Db[j] = Dv[j] + 1e-3f * norm_H; sumDb += Db[j]; }

  float M[21];
  #pragma unroll
  for (int n = 0; n < 6; ++n)
    #pragma unroll
    for (int mm = 0; mm <= n; ++mm) {
      float acc = 0.f;
      #pragma unroll
      for (int j = 0; j < 12; ++j) acc = fmaf(Jp[n][j], Jp[mm][j], acc);
      M[n * (n + 1) / 2 + mm] = acc;
    }
  float md = 0.f;
  #pragma unroll
  for (int i = 0; i < 6; ++i) md += M[i * (i + 1) / 2 + i];
  float norm_M = fmaxf(md * (1.f / 6.f) + EPSP, 1e-6f);
  #pragma unroll
  for (int i = 0; i < 6; ++i) M[i * (i + 1) / 2 + i] += EPSP + 1e-3f * norm_M;

  float trace_p = 0.f;
  #pragma unroll
  for (int n = 0; n < 6; ++n)
    #pragma unroll
    for (int j = 0; j < 12; ++j)
      trace_p = fmaf(Jp[n][j] * Jp[n][j], Db[j], trace_p);

  float trace = (EPSP + 1e-3f * norm_M) * (sumDb + tq) + trace_p + tpq;

  float ldM = 0.f;
  #pragma unroll
  for (int jc = 0; jc < 6; ++jc) {
    float d = M[jc * (jc + 1) / 2 + jc];
    #pragma unroll
    for (int k = 0; k < jc; ++k) d -= M[jc * (jc + 1) / 2 + k] * M[jc * (jc + 1) / 2 + k];
    d = sqrtf(d);
    ldM += logf(d);
    float di = 1.f / d;
    M[jc * (jc + 1) / 2 + jc] = d;
    #pragma unroll
    for (int i2 = jc + 1; i2 < 6; ++i2) {
      float v = M[i2 * (i2 + 1) / 2 + jc];
      #pragma unroll
      for (int k = 0; k < jc; ++k) v -= M[i2 * (i2 + 1) / 2 + k] * M[jc * (jc + 1) / 2 + k];
      M[i2 * (i2 + 1) / 2 + jc] = v * di;
    }
  }

  float ldH = 0.f;
  #pragma unroll
  for (int jc = 0; jc < 12; ++jc) {
    float d = Sq[jc * (jc + 1) / 2 + jc];
    #pragma unroll
    for (int k = 0; k < jc; ++k) d -= Sq[jc * (jc + 1) / 2 + k] * Sq[jc * (jc + 1) / 2 + k];
    d = sqrtf(d);
    ldH += logf(d);
    float di = 1.f / d;
    Sq[jc * (jc + 1) / 2 + jc] = d;
    #pragma unroll
    for (int i2 = jc + 1; i2 < 12; ++i2) {
      float v = Sq[i2 * (i2 + 1) / 2 + jc];
      #pragma unroll
      for (int k = 0; k < jc; ++k) v -= Sq[i2 * (i2 + 1) / 2 + k] * Sq[jc * (jc + 1) / 2 + k];
      Sq[i2 * (i2 + 1) / 2 + jc] = v * di;
    }
  }

  float logdet_p = 2.f * ldM + 6.f * logf(EPSP);
  float logdet_q = 2.f * ldH;
  out_kl[elem] = 0.5f * (trace - (logdet_p + logdet_q) - 12.f);
}

// ---------------------------------------------------------------------
extern "C" void kernel_launch(void* const* d_in, const int* in_sizes, int n_in,
                              void* d_out, int out_size, void* d_ws, size_t ws_size,
                              hipStream_t stream) {
  (void)in_sizes; (void)n_in; (void)out_size; (void)ws_size;
  float* y    = (float*)d_in[0];   // consumed, then overwritten with z
  float* Jp   = (float*)d_in[1];   // consumed, then overwritten with pullback Jp
  const float* W1   = (const float*)d_in[2];
  const float* b1   = (const float*)d_in[3];
  const float* W2   = (const float*)d_in[4];
  const float* b2   = (const float*)d_in[5];
  const float* W3   = (const float*)d_in[6];
  const float* b3   = (const float*)d_in[7];
  const float* Wsym = (const float*)d_in[8];
  const float* lvd  = (const float*)d_in[9];
  float* out = (float*)d_out;      // fp32: [log_prob (B), kl (B)]

  float* ws_sum = (float*)d_ws;
  unsigned short* w2b = (unsigned short*)((char*)d_ws + 256);
  unsigned short* w2t = (unsigned short*)((char*)d_ws + 256 +
                                          NLAYER * HID * HID * 2);
  hipMemsetAsync(d_ws, 0, 4, stream);

  prep_kernel<<<3456, 256, 0, stream>>>(W2, w2b, w2t);
  flow_kernel<<<BTOT / EPB, 512, 0, stream>>>(
      y, Jp, W1, b1, b2, W3, b3, w2b, w2t, ws_sum, out);
  kl_kernel<<<64, 256, 0, stream>>>(y, Jp, Wsym, lvd, ws_sum, out + BTOT);
}

// Round 11
// 1861.615 us; speedup vs baseline: 1.3171x; 1.0651x over previous
//
#include <hip/hip_runtime.h>
#include <hip/hip_bf16.h>
#include <math.h>

#define BTOT   16384
#define NLAYER 24
#define HID    192
#define NDIN   12
#define NBASE  66
#define EPSP   1e-3f
#define EPB    32        // elements per block; 512 threads; grid 512

// ------------- LDS layout (bytes), 122,912 total, dynamic -------------
#define EST 200          // j/k stride (shorts) for sH1b/sGb rows
#define OB_H1  0         // ushort[32*200]  12800 : h1 bf16 [e][k]
#define OB_G   12800     // ushort[192*200] 76800 : h2 rows 0-31, then G [col][j]
#define OB_R   89600     // float[72*32]     9216 : cotangent rows [rt][e]
#define OB_W1  98816     // ushort[192*8]    3072 : W1 bf16 rows padded to 8
#define OB_W3F 101888    // float[192*16]   12288 : W3 fp32 [j][t] rows padded 16
#define OB_PRM 114176    // float[2][12*32]  3072 : prm sums / tf,es (dbuf by layer parity)
#define OB_GZ  117248    // float[6*192]     4608 : g_z1 sums [i][col] (atomics)
#define OB_Z1  121856    // float[6*32]       768 : z[6..12) for next F1
#define OB_LD  122624    // float[32]         128 : logdet acc
#define OB_ZQ  122752    // float[32]         128 : sum z^2
#define OB_RED 122880    // float[8]           32
#define SMEM_BYTES 122912

typedef __attribute__((ext_vector_type(8))) short s8v;
typedef __attribute__((ext_vector_type(4))) float f4v;
#define MFMA16(a,b,c) __builtin_amdgcn_mfma_f32_16x16x32_bf16(a,b,c,0,0,0)

__device__ __forceinline__ unsigned short f2bf(float f) {
  unsigned u = __builtin_bit_cast(unsigned, f);
  u += 0x7fffu + ((u >> 16) & 1u);          // RNE
  return (unsigned short)(u >> 16);
}
__device__ __forceinline__ float bf2f(unsigned short h) {
  unsigned u = ((unsigned)h) << 16;
  return __builtin_bit_cast(float, u);
}
__device__ __forceinline__ unsigned pk2(float a, float b) {
  return (unsigned)f2bf(a) | ((unsigned)f2bf(b) << 16);
}
__device__ __forceinline__ float blo(unsigned u) { return bf2f((unsigned short)(u & 0xffff)); }
__device__ __forceinline__ float bhi(unsigned u) { return bf2f((unsigned short)(u >> 16)); }

// ---------------------------------------------------------------------
__global__ void prep_kernel(const float* __restrict__ W2,
                            unsigned short* __restrict__ w2b,
                            unsigned short* __restrict__ w2t) {
  int idx = blockIdx.x * 256 + threadIdx.x;   // 884736 exact
  int l   = idx / (HID * HID);
  int rem = idx - l * HID * HID;
  int k   = rem / HID;
  int j   = rem - k * HID;
  w2b[idx] = f2bf(W2[idx]);                         // [l][j][k]
  w2t[idx] = f2bf(W2[l * HID * HID + j * HID + k]); // [l][k][j]
}

// ---------------------------------------------------------------------
// flow_kernel: block = 32 elements, 512 threads (8 waves), grid 512.
// 5 barriers/layer (was 7): S2 folded into S1's MFMA epilogue (h2 stays
// in registers); V5 folded into next layer's F1 phase (sPRM dbuf'd by
// layer parity). V3 = 192x192x192 GEMM in 2 n-half passes (acc stays 36
// regs). NO register caps: R5/R6/R8/R10 all showed cap => spill >= gain.
// Occupancy axis closed (R10): natural demand ~136 combined regs vs 128
// needed for 2 blocks; spill and occupancy cancel. This round halves
// barrier-drain events instead: 2 rounds/CU x 24 x 5 vs 4 x 24 x 7.
__global__ __launch_bounds__(512) void flow_kernel(
    float* __restrict__ yz, float* __restrict__ jp,
    const float* __restrict__ W1, const float* __restrict__ b1,
    const float* __restrict__ b2,
    const float* __restrict__ W3, const float* __restrict__ b3,
    const unsigned short* __restrict__ w2b,
    const unsigned short* __restrict__ w2t,
    float* __restrict__ ws_sum, float* __restrict__ out_lp) {
  extern __shared__ char smraw[];
  unsigned short* sH1b = (unsigned short*)(smraw + OB_H1);
  unsigned short* sGb  = (unsigned short*)(smraw + OB_G);
  float* sW3f = (float*)(smraw + OB_W3F);
  float* sR   = (float*)(smraw + OB_R);
  float* sPRM = (float*)(smraw + OB_PRM);   // 2 x 384 floats
  float* sGZ  = (float*)(smraw + OB_GZ);
  float* sZ1  = (float*)(smraw + OB_Z1);
  float* sLD  = (float*)(smraw + OB_LD);
  float* sZQ  = (float*)(smraw + OB_ZQ);
  float* sRed = (float*)(smraw + OB_RED);

  const int tid  = threadIdx.x;
  const int lane = tid & 63;
  const int w    = __builtin_amdgcn_readfirstlane(tid >> 6);
  const int e    = tid & 31;                     // element (scalar phases)
  const int grp  = tid >> 5;                     // 0..15
  const int lm   = lane & 15, lq = lane >> 4;    // MFMA lane coords
  const int mtg  = (w & 3) * 3;                  // m-tile base {0,3,6,9}
  const int blk  = blockIdx.x;

  // ---- init ----
  float z_a = 0.f, z_b = 0.f;     // z[i], z[6+i] held by tid<192 (i=grp)
  if (tid < 192) {
    int i = grp;
    z_a = yz[(blk * EPB + e) * 12 + i];
    z_b = yz[(blk * EPB + e) * 12 + 6 + i];
    sZ1[i * EPB + e] = z_b;
  }
  if (tid < 32) { sLD[tid] = 0.f; sZQ[tid] = 0.f; }
  if (tid == 0) sRed[0] = 0.f;
  for (int idx = tid; idx < 1152; idx += 512) sGZ[idx] = 0.f;
  for (int idx = tid; idx < 768; idx += 512) sPRM[idx] = 0.f;
  for (int idx = tid; idx < 72 * EPB; idx += 512) {
    int rt = idx >> 5, ee = idx & 31;
    sR[idx] = jp[(blk * EPB + ee) * 72 + rt];
  }
  __syncthreads();

  for (int l = NLAYER - 1; l >= 0; --l) {
    const float* W1l = W1 + l * HID * 6;
    const float* b1l = b1 + l * HID;
    const float* b2l = b2 + l * HID;
    const float* W3l = W3 + l * NDIN * HID;
    const float* b3l = b3 + l * NDIN;
    const unsigned short* w2bl = w2b + l * HID * HID;
    const unsigned short* w2tl = w2t + l * HID * HID;
    float* cur = sPRM + (l & 1) * 384;          // this layer's prm/tf/es
    float* prv = sPRM + ((l + 1) & 1) * 384;    // previous layer's tf/es

    // ==== Phase A (merged): stage W1+W3f, zero cur, V5(l+1), F1(l) ======
    if (tid < 192) {
      const float* wr = W1l + tid * 6;
      uint4 pk;
      pk.x = pk2(wr[0], wr[1]); pk.y = pk2(wr[2], wr[3]);
      pk.z = pk2(wr[4], wr[5]); pk.w = 0;
      *(uint4*)(smraw + OB_W1 + tid * 16) = pk;
    }
    for (int idx = tid; idx < 2304; idx += 512) {   // W3f [j][t], t-major read
      int t = idx / 192, j = idx - t * 192;
      sW3f[j * 16 + t] = W3l[idx];
    }
    if (tid < 384) cur[tid] = 0.f;
    if (l != NLAYER - 1) {                          // V5 of layer l+1
      for (int idx = tid; idx < 1152; idx += 512) {
        int i = idx / 192, rem = idx - i * 192;
        int r = rem >> 5, e5 = rem & 31;
        float r1  = sR[(r * 12 + i) * EPB + e5];
        float r2o = sR[(r * 12 + 6 + i) * EPB + e5];
        float es  = prv[(2 * i + 1) * EPB + e5];
        sR[(r * 12 + i) * EPB + e5]     = r2o + sGZ[i * 192 + rem];
        sR[(r * 12 + 6 + i) * EPB + e5] = r1 * es;
        sGZ[i * 192 + rem] = 0.f;
      }
    }
    {                                               // F1: h1 = relu(W1 z1+b1)
      float z1v[6];
      #pragma unroll
      for (int i = 0; i < 6; ++i) z1v[i] = sZ1[i * EPB + e];
      int jb12 = grp * 12;
      #pragma unroll
      for (int jj = 0; jj < 12; ++jj) {
        int j = jb12 + jj;
        float acc = b1l[j];
        #pragma unroll
        for (int i = 0; i < 6; ++i) acc = fmaf(W1l[j * 6 + i], z1v[i], acc);
        sH1b[e * EST + j] = f2bf(fmaxf(acc, 0.f));
      }
    }
    __syncthreads();

    // ==== Phase B: S1 = F2 MFMA (all 8 waves) + prm epilogue (was S2) ===
    {
      const int nt1 = w >> 2;                       // 0..1
      f4v acc3[3] = {{0,0,0,0},{0,0,0,0},{0,0,0,0}};
      #pragma unroll 2
      for (int kk = 0; kk < 6; ++kk) {
        int jo = kk * 32 + lq * 8;
        s8v B = *(const s8v*)&sH1b[(nt1 * 16 + lm) * EST + jo];
        #pragma unroll
        for (int p = 0; p < 3; ++p) {
          s8v A = *(const s8v*)(w2bl + ((mtg + p) * 16 + lm) * HID + jo);
          acc3[p] = MFMA16(A, B, acc3[p]);
        }
      }
      int e2 = nt1 * 16 + lm;
      float pp[12];
      #pragma unroll
      for (int t = 0; t < 12; ++t) pp[t] = 0.f;
      #pragma unroll
      for (int p = 0; p < 3; ++p) {
        int jb2 = (mtg + p) * 16 + lq * 4;
        float hv[4];
        #pragma unroll
        for (int rg = 0; rg < 4; ++rg)
          hv[rg] = fmaxf(acc3[p][rg] + b2l[jb2 + rg], 0.f);
        unsigned* dst = (unsigned*)sGb + ((e2 * EST + jb2) >> 1);
        dst[0] = pk2(hv[0], hv[1]);
        dst[1] = pk2(hv[2], hv[3]);
        #pragma unroll
        for (int rg = 0; rg < 4; ++rg) {            // prm partials, fp32 W3
          const float* w3r = sW3f + (jb2 + rg) * 16;
          float v = hv[rg];
          #pragma unroll
          for (int t = 0; t < 12; ++t) pp[t] = fmaf(w3r[t], v, pp[t]);
        }
      }
      #pragma unroll
      for (int t = 0; t < 12; ++t) {
        float v = pp[t];
        v += __shfl_xor(v, 16);
        v += __shfl_xor(v, 32);
        if (lane < 16) atomicAdd(&cur[t * EPB + nt1 * 16 + lane], v);
      }
    }
    __syncthreads();

    // ==== Phase C: U — coupling update; cur becomes tf@2i, es@2i+1 ======
    if (tid < 192) {
      int i = grp;
      float sh = b3l[2 * i]     + cur[(2 * i) * EPB + e];
      float sr = b3l[2 * i + 1] + cur[(2 * i + 1) * EPB + e];
      float s  = 2.f * tanhf(0.5f * sr);
      float es = expf(s), en = expf(-s);
      float tv = z_a - sh;
      z_a = z_b;
      z_b = tv * en;
      sZ1[i * EPB + e] = z_b;
      cur[(2 * i) * EPB + e]     = tv * (1.f - 0.25f * s * s);  // tf
      cur[(2 * i + 1) * EPB + e] = es;                          // es
      atomicAdd(&sLD[e], -s);
    }
    __syncthreads();

    // ==== Phase D: V2 (all 6 rows, 2 j-slab tasks per thread) ===========
    {
      float tf[6];
      #pragma unroll
      for (int i = 0; i < 6; ++i) tf[i] = cur[(2 * i) * EPB + e];
      #pragma unroll 1
      for (int t2 = 0; t2 < 2; ++t2) {
        int slab = (grp + 16 * t2) * 6;
        const unsigned* hp = (const unsigned*)&sGb[e * EST + slab];
        unsigned h2d0 = hp[0], h2d1 = hp[1], h2d2 = hp[2];
        float weff[6][6];
        #pragma unroll
        for (int jj = 0; jj < 6; ++jj) {
          const float* wrow = sW3f + (slab + jj) * 16;
          #pragma unroll
          for (int c = 0; c < 6; ++c)
            weff[jj][c] = fmaf(tf[c], wrow[2 * c + 1], wrow[2 * c]);
        }
        #pragma unroll
        for (int r = 0; r < 6; ++r) {
          float g[6] = {0.f, 0.f, 0.f, 0.f, 0.f, 0.f};
          #pragma unroll
          for (int c = 0; c < 6; ++c) {
            float r1 = sR[(r * 12 + c) * EPB + e];
            #pragma unroll
            for (int jj = 0; jj < 6; ++jj)
              g[jj] = fmaf(weff[jj][c], r1, g[jj]);
          }
          unsigned* dst = (unsigned*)sGb + (((r * EPB + e) * EST + slab) >> 1);
          float v0 = (h2d0 & 0xffffu) ? g[0] : 0.f;
          float v1 = (h2d0 >> 16)     ? g[1] : 0.f;
          float v2 = (h2d1 & 0xffffu) ? g[2] : 0.f;
          float v3 = (h2d1 >> 16)     ? g[3] : 0.f;
          float v4 = (h2d2 & 0xffffu) ? g[4] : 0.f;
          float v5 = (h2d2 >> 16)     ? g[5] : 0.f;
          dst[0] = pk2(v0, v1); dst[1] = pk2(v2, v3); dst[2] = pk2(v4, v5);
        }
      }
    }
    __syncthreads();

    // ==== Phase E: V3 = 192x192x192 GEMM in 2 n-half passes + epilogue ==
    #pragma unroll 1
    for (int h = 0; h < 2; ++h) {
      int ntb = (w >> 2) * 3 + h * 6;               // n-tile base
      f4v acc[3][3] = {{{0,0,0,0},{0,0,0,0},{0,0,0,0}},
                       {{0,0,0,0},{0,0,0,0},{0,0,0,0}},
                       {{0,0,0,0},{0,0,0,0},{0,0,0,0}}};
      #pragma unroll 2
      for (int kk = 0; kk < 6; ++kk) {
        int jo = kk * 32 + lq * 8;
        s8v A[3], B[3];
        #pragma unroll
        for (int p = 0; p < 3; ++p)
          A[p] = *(const s8v*)(w2tl + ((mtg + p) * 16 + lm) * HID + jo);
        #pragma unroll
        for (int q = 0; q < 3; ++q)
          B[q] = *(const s8v*)&sGb[((ntb + q) * 16 + lm) * EST + jo];
        #pragma unroll
        for (int p = 0; p < 3; ++p)
          #pragma unroll
          for (int q = 0; q < 3; ++q)
            acc[p][q] = MFMA16(A[p], B[q], acc[p][q]);
      }
      float pz[3][6];
      #pragma unroll
      for (int q = 0; q < 3; ++q)
        #pragma unroll
        for (int i = 0; i < 6; ++i) pz[q][i] = 0.f;
      #pragma unroll
      for (int p = 0; p < 3; ++p) {
        int kb = (mtg + p) * 16 + lq * 4;
        float w1v[4][6];
        #pragma unroll
        for (int rg = 0; rg < 4; ++rg) {
          uint4 wr = *(const uint4*)(smraw + OB_W1 + (kb + rg) * 16);
          w1v[rg][0] = blo(wr.x); w1v[rg][1] = bhi(wr.x);
          w1v[rg][2] = blo(wr.y); w1v[rg][3] = bhi(wr.y);
          w1v[rg][4] = blo(wr.z); w1v[rg][5] = bhi(wr.z);
        }
        #pragma unroll
        for (int q = 0; q < 3; ++q) {
          int e31 = (((ntb + q) & 1) << 4) + lm;    // col & 31
          const unsigned* mp = (const unsigned*)&sH1b[e31 * EST + kb];
          unsigned mm0 = mp[0], mm1 = mp[1];
          unsigned short hb[4] = {
            (unsigned short)(mm0 & 0xffff), (unsigned short)(mm0 >> 16),
            (unsigned short)(mm1 & 0xffff), (unsigned short)(mm1 >> 16)};
          #pragma unroll
          for (int rg = 0; rg < 4; ++rg) {
            float val = hb[rg] ? acc[p][q][rg] : 0.f;
            #pragma unroll
            for (int i = 0; i < 6; ++i)
              pz[q][i] = fmaf(w1v[rg][i], val, pz[q][i]);
          }
        }
      }
      #pragma unroll
      for (int q = 0; q < 3; ++q)
        #pragma unroll
        for (int i = 0; i < 6; ++i) {
          float v = pz[q][i];
          v += __shfl_xor(v, 16);
          v += __shfl_xor(v, 32);
          if (lane < 16) atomicAdd(&sGZ[i * 192 + (ntb + q) * 16 + lane], v);
        }
    }
    __syncthreads();
  }

  // ---- final V5 (layer 0, parity 0) + z/lp; then jp writeback ----
  {
    float* prv0 = sPRM;                             // (0 & 1) == 0
    for (int idx = tid; idx < 1152; idx += 512) {
      int i = idx / 192, rem = idx - i * 192;
      int r = rem >> 5, e5 = rem & 31;
      float r1  = sR[(r * 12 + i) * EPB + e5];
      float r2o = sR[(r * 12 + 6 + i) * EPB + e5];
      float es  = prv0[(2 * i + 1) * EPB + e5];
      sR[(r * 12 + i) * EPB + e5]     = r2o + sGZ[i * 192 + rem];
      sR[(r * 12 + 6 + i) * EPB + e5] = r1 * es;
    }
  }
  if (tid < 192) {
    int i = grp;
    yz[(blk * EPB + e) * 12 + i]     = z_a;
    yz[(blk * EPB + e) * 12 + 6 + i] = z_b;
    atomicAdd(&sZQ[e], fmaf(z_a, z_a, z_b * z_b));
  }
  __syncthreads();
  if (tid < 32)
    out_lp[blk * EPB + tid] = sLD[tid] - 11.027262398456072f - 0.5f * sZQ[tid];

  float part = 0.f;
  for (int idx = tid; idx < 72 * EPB; idx += 512) {
    int rt = idx >> 5, ee = idx & 31;
    float v = sR[idx];
    jp[(blk * EPB + ee) * 72 + rt] = v;
    part = fmaf(v, v, part);
  }
  #pragma unroll
  for (int off = 32; off > 0; off >>= 1) part += __shfl_down(part, off, 64);
  if ((tid & 63) == 0) atomicAdd(&sRed[0], part);
  __syncthreads();
  if (tid == 0) atomicAdd(ws_sum, sRed[0]);
}

// ---------------------------------------------------------------------
// kl_kernel: one thread per element (unchanged from R3..R10 PASS).
__global__ __launch_bounds__(256) void kl_kernel(
    const float* __restrict__ zin, const float* __restrict__ jpin,
    const float* __restrict__ Wsym, const float* __restrict__ lvd,
    const float* __restrict__ ws_sum, float* __restrict__ out_kl) {
  int elem = blockIdx.x * 256 + threadIdx.x;
  float z[12];
  #pragma unroll
  for (int i = 0; i < 12; ++i) z[i] = zin[elem * 12 + i];
  float scale = 1.0f / sqrtf(ws_sum[0]);
  float Jp[6][12];
  #pragma unroll
  for (int n = 0; n < 6; ++n)
    #pragma unroll
    for (int j = 0; j < 12; ++j)
      Jp[n][j] = jpin[elem * 72 + n * 12 + j] * scale;

  float Sq[78];
  #pragma unroll
  for (int i = 0; i < 78; ++i) Sq[i] = 0.f;
  float tq = 0.f, tpq = 0.f;

  for (int m = 0; m < NBASE; ++m) {
    const float* Wm = Wsym + m * 144;
    float jq[12];
    #pragma unroll
    for (int j = 0; j < 12; ++j) {
      float acc = 0.f;
      #pragma unroll
      for (int i = 0; i < 12; ++i)
        acc = fmaf(Wm[j * 12 + i] - Wm[i * 12 + j], z[i], acc);
      jq[j] = acc;
    }
    #pragma unroll
    for (int i = 0; i < 12; ++i) {
      tq = fmaf(jq[i], jq[i], tq);
      #pragma unroll
      for (int j = 0; j <= i; ++j)
        Sq[i * (i + 1) / 2 + j] = fmaf(jq[i], jq[j], Sq[i * (i + 1) / 2 + j]);
    }
    #pragma unroll
    for (int n = 0; n < 6; ++n) {
      float d = 0.f;
      #pragma unroll
      for (int j = 0; j < 12; ++j) d = fmaf(Jp[n][j], jq[j], d);
      tpq = fmaf(d, d, tpq);
    }
  }

  float Dv[12], Db[12];
  #pragma unroll
  for (int j = 0; j < 12; ++j) Dv[j] = expf(-lvd[j]);

  float mh = 0.f;
  #pragma unroll
  for (int i = 0; i < 12; ++i) mh += Sq[i * (i + 1) / 2 + i] + Dv[i];
  float norm_H = fmaxf(mh * (1.f / 12.f), 1e-6f);
  #pragma unroll
  for (int i = 0; i < 12; ++i) Sq[i * (i + 1) / 2 + i] += Dv[i] + 1e-3f * norm_H;
  float sumDb = 0.f;
  #pragma unroll
  for (int j = 0; j < 12; ++j) { Db[j] = Dv[j] + 1e-3f * norm_H; sumDb += Db[j]; }

  float M[21];
  #pragma unroll
  for (int n = 0; n < 6; ++n)
    #pragma unroll
    for (int mm = 0; mm <= n; ++mm) {
      float acc = 0.f;
      #pragma unroll
      for (int j = 0; j < 12; ++j) acc = fmaf(Jp[n][j], Jp[mm][j], acc);
      M[n * (n + 1) / 2 + mm] = acc;
    }
  float md = 0.f;
  #pragma unroll
  for (int i = 0; i < 6; ++i) md += M[i * (i + 1) / 2 + i];
  float norm_M = fmaxf(md * (1.f / 6.f) + EPSP, 1e-6f);
  #pragma unroll
  for (int i = 0; i < 6; ++i) M[i * (i + 1) / 2 + i] += EPSP + 1e-3f * norm_M;

  float trace_p = 0.f;
  #pragma unroll
  for (int n = 0; n < 6; ++n)
    #pragma unroll
    for (int j = 0; j < 12; ++j)
      trace_p = fmaf(Jp[n][j] * Jp[n][j], Db[j], trace_p);

  float trace = (EPSP + 1e-3f * norm_M) * (sumDb + tq) + trace_p + tpq;

  float ldM = 0.f;
  #pragma unroll
  for (int jc = 0; jc < 6; ++jc) {
    float d = M[jc * (jc + 1) / 2 + jc];
    #pragma unroll
    for (int k = 0; k < jc; ++k) d -= M[jc * (jc + 1) / 2 + k] * M[jc * (jc + 1) / 2 + k];
    d = sqrtf(d);
    ldM += logf(d);
    float di = 1.f / d;
    M[jc * (jc + 1) / 2 + jc] = d;
    #pragma unroll
    for (int i2 = jc + 1; i2 < 6; ++i2) {
      float v = M[i2 * (i2 + 1) / 2 + jc];
      #pragma unroll
      for (int k = 0; k < jc; ++k) v -= M[i2 * (i2 + 1) / 2 + k] * M[jc * (jc + 1) / 2 + k];
      M[i2 * (i2 + 1) / 2 + jc] = v * di;
    }
  }

  float ldH = 0.f;
  #pragma unroll
  for (int jc = 0; jc < 12; ++jc) {
    float d = Sq[jc * (jc + 1) / 2 + jc];
    #pragma unroll
    for (int k = 0; k < jc; ++k) d -= Sq[jc * (jc + 1) / 2 + k] * Sq[jc * (jc + 1) / 2 + k];
    d = sqrtf(d);
    ldH += logf(d);
    float di = 1.f / d;
    Sq[jc * (jc + 1) / 2 + jc] = d;
    #pragma unroll
    for (int i2 = jc + 1; i2 < 12; ++i2) {
      float v = Sq[i2 * (i2 + 1) / 2 + jc];
      #pragma unroll
      for (int k = 0; k < jc; ++k) v -= Sq[i2 * (i2 + 1) / 2 + k] * Sq[jc * (jc + 1) / 2 + k];
      Sq[i2 * (i2 + 1) / 2 + jc] = v * di;
    }
  }

  float logdet_p = 2.f * ldM + 6.f * logf(EPSP);
  float logdet_q = 2.f * ldH;
  out_kl[elem] = 0.5f * (trace - (logdet_p + logdet_q) - 12.f);
}

// ---------------------------------------------------------------------
extern "C" void kernel_launch(void* const* d_in, const int* in_sizes, int n_in,
                              void* d_out, int out_size, void* d_ws, size_t ws_size,
                              hipStream_t stream) {
  (void)in_sizes; (void)n_in; (void)out_size; (void)ws_size;
  float* y    = (float*)d_in[0];   // consumed, then overwritten with z
  float* Jp   = (float*)d_in[1];   // consumed, then overwritten with pullback Jp
  const float* W1   = (const float*)d_in[2];
  const float* b1   = (const float*)d_in[3];
  const float* W2   = (const float*)d_in[4];
  const float* b2   = (const float*)d_in[5];
  const float* W3   = (const float*)d_in[6];
  const float* b3   = (const float*)d_in[7];
  const float* Wsym = (const float*)d_in[8];
  const float* lvd  = (const float*)d_in[9];
  float* out = (float*)d_out;      // fp32: [log_prob (B), kl (B)]

  float* ws_sum = (float*)d_ws;
  unsigned short* w2b = (unsigned short*)((char*)d_ws + 256);
  unsigned short* w2t = (unsigned short*)((char*)d_ws + 256 +
                                          NLAYER * HID * HID * 2);
  hipMemsetAsync(d_ws, 0, 4, stream);

  hipFuncSetAttribute((const void*)flow_kernel,
                      hipFuncAttributeMaxDynamicSharedMemorySize, SMEM_BYTES);

  prep_kernel<<<3456, 256, 0, stream>>>(W2, w2b, w2t);
  flow_kernel<<<BTOT / EPB, 512, SMEM_BYTES, stream>>>(
      y, Jp, W1, b1, b2, W3, b3, w2b, w2t, ws_sum, out);
  kl_kernel<<<64, 256, 0, stream>>>(y, Jp, Wsym, lvd, ws_sum, out + BTOT);
}

// Round 12
// 1837.416 us; speedup vs baseline: 1.3344x; 1.0132x over previous
//
#include <hip/hip_runtime.h>
#include <hip/hip_bf16.h>
#include <math.h>

#define BTOT   16384
#define NLAYER 24
#define HID    192
#define NDIN   12
#define NBASE  66
#define EPSP   1e-3f
#define EPB    32        // elements per block; 768 threads; grid 512

// ------------- LDS layout (bytes), 123,680 total, dynamic -------------
#define EST 200          // j/k stride (shorts) for sH1b/sGb rows
#define W3ST 17          // sW3f row stride in floats (17 -> full bank rotation)
#define OB_H1  0         // ushort[32*200]  12800 : h1 bf16 [e][k]
#define OB_G   12800     // ushort[192*200] 76800 : h2 rows 0-31, then G [col][j]
#define OB_R   89600     // float[72*32]     9216 : cotangent rows [rt][e]
#define OB_W1  98816     // ushort[192*8]    3072 : W1 bf16 rows padded to 8
#define OB_W3F 101888    // float[192*17]   13056 : W3 fp32 [j][t], stride 17
#define OB_PRM 114944    // float[2][12*32]  3072 : prm sums / tf,es (layer-parity dbuf)
#define OB_GZ  118016    // float[6*192]     4608 : g_z1 sums [i][col] (atomics)
#define OB_Z1  122624    // float[6*32]       768 : z[6..12) for next F1
#define OB_LD  123392    // float[32]         128 : logdet acc
#define OB_ZQ  123520    // float[32]         128 : sum z^2
#define OB_RED 123648    // float[8]           32
#define SMEM_BYTES 123680

typedef __attribute__((ext_vector_type(8))) short s8v;
typedef __attribute__((ext_vector_type(4))) float f4v;
#define MFMA16(a,b,c) __builtin_amdgcn_mfma_f32_16x16x32_bf16(a,b,c,0,0,0)

__device__ __forceinline__ unsigned short f2bf(float f) {
  unsigned u = __builtin_bit_cast(unsigned, f);
  u += 0x7fffu + ((u >> 16) & 1u);          // RNE
  return (unsigned short)(u >> 16);
}
__device__ __forceinline__ float bf2f(unsigned short h) {
  unsigned u = ((unsigned)h) << 16;
  return __builtin_bit_cast(float, u);
}
__device__ __forceinline__ unsigned pk2(float a, float b) {
  return (unsigned)f2bf(a) | ((unsigned)f2bf(b) << 16);
}
__device__ __forceinline__ float blo(unsigned u) { return bf2f((unsigned short)(u & 0xffff)); }
__device__ __forceinline__ float bhi(unsigned u) { return bf2f((unsigned short)(u >> 16)); }

// ---------------------------------------------------------------------
__global__ void prep_kernel(const float* __restrict__ W2,
                            unsigned short* __restrict__ w2b,
                            unsigned short* __restrict__ w2t) {
  int idx = blockIdx.x * 256 + threadIdx.x;   // 884736 exact
  int l   = idx / (HID * HID);
  int rem = idx - l * HID * HID;
  int k   = rem / HID;
  int j   = rem - k * HID;
  w2b[idx] = f2bf(W2[idx]);                         // [l][j][k]
  w2t[idx] = f2bf(W2[l * HID * HID + j * HID + k]); // [l][k][j]
}

// ---------------------------------------------------------------------
// flow_kernel: block = 32 elements, 768 threads = 12 waves = 3 waves/SIMD
// (guaranteed co-resident; bypasses the multi-block residency wall of
// R3-R10). Natural reg demand ~140-150 combined fits the 170/wave budget
// at 3 waves/SIMD -> no caps, no spill (caps spilled in R5/R6/R8/R10).
// 5 barriers/layer (R11 merge). V3 single-pass 3x4 tiles/wave (w2t
// streamed once/layer). sW3f stride 17 kills the R11 4-way row aliasing.
__global__ __launch_bounds__(768) void flow_kernel(
    float* __restrict__ yz, float* __restrict__ jp,
    const float* __restrict__ W1, const float* __restrict__ b1,
    const float* __restrict__ b2,
    const float* __restrict__ W3, const float* __restrict__ b3,
    const unsigned short* __restrict__ w2b,
    const unsigned short* __restrict__ w2t,
    float* __restrict__ ws_sum, float* __restrict__ out_lp) {
  extern __shared__ char smraw[];
  unsigned short* sH1b = (unsigned short*)(smraw + OB_H1);
  unsigned short* sGb  = (unsigned short*)(smraw + OB_G);
  float* sW3f = (float*)(smraw + OB_W3F);
  float* sR   = (float*)(smraw + OB_R);
  float* sPRM = (float*)(smraw + OB_PRM);   // 2 x 384 floats
  float* sGZ  = (float*)(smraw + OB_GZ);
  float* sZ1  = (float*)(smraw + OB_Z1);
  float* sLD  = (float*)(smraw + OB_LD);
  float* sZQ  = (float*)(smraw + OB_ZQ);
  float* sRed = (float*)(smraw + OB_RED);

  const int tid  = threadIdx.x;
  const int lane = tid & 63;
  const int w    = __builtin_amdgcn_readfirstlane(tid >> 6);  // 0..11
  const int e    = tid & 31;                     // element (scalar phases)
  const int grp  = tid >> 5;                     // 0..23
  const int lm   = lane & 15, lq = lane >> 4;    // MFMA lane coords
  const int blk  = blockIdx.x;

  // ---- init ----
  float z_a = 0.f, z_b = 0.f;     // z[i], z[6+i] held by tid<192 (i=grp)
  if (tid < 192) {
    int i = grp;
    z_a = yz[(blk * EPB + e) * 12 + i];
    z_b = yz[(blk * EPB + e) * 12 + 6 + i];
    sZ1[i * EPB + e] = z_b;
  }
  if (tid < 32) { sLD[tid] = 0.f; sZQ[tid] = 0.f; }
  if (tid == 0) sRed[0] = 0.f;
  for (int idx = tid; idx < 1152; idx += 768) sGZ[idx] = 0.f;
  if (tid < 768) sPRM[tid] = 0.f;
  for (int idx = tid; idx < 72 * EPB; idx += 768) {
    int rt = idx >> 5, ee = idx & 31;
    sR[idx] = jp[(blk * EPB + ee) * 72 + rt];
  }
  __syncthreads();

  for (int l = NLAYER - 1; l >= 0; --l) {
    const float* W1l = W1 + l * HID * 6;
    const float* b1l = b1 + l * HID;
    const float* b2l = b2 + l * HID;
    const float* W3l = W3 + l * NDIN * HID;
    const float* b3l = b3 + l * NDIN;
    const unsigned short* w2bl = w2b + l * HID * HID;
    const unsigned short* w2tl = w2t + l * HID * HID;
    float* cur = sPRM + (l & 1) * 384;          // this layer's prm/tf/es
    float* prv = sPRM + ((l + 1) & 1) * 384;    // previous layer's tf/es

    // ==== Phase A (merged): stage W1+W3f, zero cur, V5(l+1), F1(l) ======
    if (tid < 192) {
      const float* wr = W1l + tid * 6;
      uint4 pk;
      pk.x = pk2(wr[0], wr[1]); pk.y = pk2(wr[2], wr[3]);
      pk.z = pk2(wr[4], wr[5]); pk.w = 0;
      *(uint4*)(smraw + OB_W1 + tid * 16) = pk;
    }
    for (int idx = tid; idx < 2304; idx += 768) {   // W3f [j][t], stride 17
      int t = idx / 192, j = idx - t * 192;
      sW3f[j * W3ST + t] = W3l[idx];
    }
    if (tid < 384) cur[tid] = 0.f;
    if (l != NLAYER - 1) {                          // V5 of layer l+1
      for (int idx = tid; idx < 1152; idx += 768) {
        int i = idx / 192, rem = idx - i * 192;
        int r = rem >> 5, e5 = rem & 31;
        float r1  = sR[(r * 12 + i) * EPB + e5];
        float r2o = sR[(r * 12 + 6 + i) * EPB + e5];
        float es  = prv[(2 * i + 1) * EPB + e5];
        sR[(r * 12 + i) * EPB + e5]     = r2o + sGZ[i * 192 + rem];
        sR[(r * 12 + 6 + i) * EPB + e5] = r1 * es;
        sGZ[i * 192 + rem] = 0.f;
      }
    }
    {                                               // F1: 8 rows per grp
      float z1v[6];
      #pragma unroll
      for (int i = 0; i < 6; ++i) z1v[i] = sZ1[i * EPB + e];
      int jb8 = grp * 8;
      #pragma unroll
      for (int jj = 0; jj < 8; ++jj) {
        int j = jb8 + jj;
        float acc = b1l[j];
        #pragma unroll
        for (int i = 0; i < 6; ++i) acc = fmaf(W1l[j * 6 + i], z1v[i], acc);
        sH1b[e * EST + j] = f2bf(fmaxf(acc, 0.f));
      }
    }
    __syncthreads();

    // ==== Phase B: S1 = F2 MFMA (1 m-tile x 2 n-tiles/wave) + prm epi ===
    {
      f4v acc2[2] = {{0,0,0,0},{0,0,0,0}};
      #pragma unroll 2
      for (int kk = 0; kk < 6; ++kk) {
        int jo = kk * 32 + lq * 8;
        s8v A  = *(const s8v*)(w2bl + (w * 16 + lm) * HID + jo);
        s8v B0 = *(const s8v*)&sH1b[lm * EST + jo];
        s8v B1 = *(const s8v*)&sH1b[(16 + lm) * EST + jo];
        acc2[0] = MFMA16(A, B0, acc2[0]);
        acc2[1] = MFMA16(A, B1, acc2[1]);
      }
      int jb2 = w * 16 + lq * 4;
      float pp[2][12];
      #pragma unroll
      for (int nt = 0; nt < 2; ++nt)
        #pragma unroll
        for (int t = 0; t < 12; ++t) pp[nt][t] = 0.f;
      #pragma unroll
      for (int nt = 0; nt < 2; ++nt) {
        int e2 = nt * 16 + lm;
        float hv[4];
        #pragma unroll
        for (int rg = 0; rg < 4; ++rg)
          hv[rg] = fmaxf(acc2[nt][rg] + b2l[jb2 + rg], 0.f);
        unsigned* dst = (unsigned*)sGb + ((e2 * EST + jb2) >> 1);
        dst[0] = pk2(hv[0], hv[1]);
        dst[1] = pk2(hv[2], hv[3]);
        #pragma unroll
        for (int rg = 0; rg < 4; ++rg) {
          const float* w3r = sW3f + (jb2 + rg) * W3ST;
          float v = hv[rg];
          #pragma unroll
          for (int t = 0; t < 12; ++t) pp[nt][t] = fmaf(w3r[t], v, pp[nt][t]);
        }
      }
      #pragma unroll
      for (int nt = 0; nt < 2; ++nt)
        #pragma unroll
        for (int t = 0; t < 12; ++t) {
          float v = pp[nt][t];
          v += __shfl_xor(v, 16);
          v += __shfl_xor(v, 32);
          if (lane < 16) atomicAdd(&cur[t * EPB + nt * 16 + lane], v);
        }
    }
    __syncthreads();

    // ==== Phase C: U — coupling update; cur becomes tf@2i, es@2i+1 ======
    if (tid < 192) {
      int i = grp;
      float sh = b3l[2 * i]     + cur[(2 * i) * EPB + e];
      float sr = b3l[2 * i + 1] + cur[(2 * i + 1) * EPB + e];
      float s  = 2.f * tanhf(0.5f * sr);
      float es = expf(s), en = expf(-s);
      float tv = z_a - sh;
      z_a = z_b;
      z_b = tv * en;
      sZ1[i * EPB + e] = z_b;
      cur[(2 * i) * EPB + e]     = tv * (1.f - 0.25f * s * s);  // tf
      cur[(2 * i + 1) * EPB + e] = es;                          // es
      atomicAdd(&sLD[e], -s);
    }
    __syncthreads();

    // ==== Phase D: V2 (all 6 rows, one 8-wide j-slab per thread) ========
    {
      float tf[6];
      #pragma unroll
      for (int i = 0; i < 6; ++i) tf[i] = cur[(2 * i) * EPB + e];
      int slab = grp * 8;
      const unsigned* hp = (const unsigned*)&sGb[e * EST + slab];
      unsigned h2d[4];
      #pragma unroll
      for (int c = 0; c < 4; ++c) h2d[c] = hp[c];
      float weff[8][6];
      #pragma unroll
      for (int jj = 0; jj < 8; ++jj) {
        const float* wrow = sW3f + (slab + jj) * W3ST;
        #pragma unroll
        for (int c = 0; c < 6; ++c)
          weff[jj][c] = fmaf(tf[c], wrow[2 * c + 1], wrow[2 * c]);
      }
      #pragma unroll
      for (int r = 0; r < 6; ++r) {
        float g[8];
        #pragma unroll
        for (int jj = 0; jj < 8; ++jj) g[jj] = 0.f;
        #pragma unroll
        for (int c = 0; c < 6; ++c) {
          float r1 = sR[(r * 12 + c) * EPB + e];
          #pragma unroll
          for (int jj = 0; jj < 8; ++jj)
            g[jj] = fmaf(weff[jj][c], r1, g[jj]);
        }
        unsigned* dst = (unsigned*)sGb + (((r * EPB + e) * EST + slab) >> 1);
        #pragma unroll
        for (int pr = 0; pr < 4; ++pr) {
          float v0 = (h2d[pr] & 0xffffu) ? g[2 * pr] : 0.f;
          float v1 = (h2d[pr] >> 16)     ? g[2 * pr + 1] : 0.f;
          dst[pr] = pk2(v0, v1);
        }
      }
    }
    __syncthreads();

    // ==== Phase E: V3 single pass, 3x4 tiles/wave + epilogue -> sGZ =====
    {
      const int mtg3 = (w & 3) * 3;                // {0,3,6,9}
      const int ntg4 = (w >> 2) * 4;               // {0,4,8}
      f4v acc[3][4] = {{{0,0,0,0},{0,0,0,0},{0,0,0,0},{0,0,0,0}},
                       {{0,0,0,0},{0,0,0,0},{0,0,0,0},{0,0,0,0}},
                       {{0,0,0,0},{0,0,0,0},{0,0,0,0},{0,0,0,0}}};
      #pragma unroll 2
      for (int kk = 0; kk < 6; ++kk) {
        int jo = kk * 32 + lq * 8;
        s8v A[3], B[4];
        #pragma unroll
        for (int p = 0; p < 3; ++p)
          A[p] = *(const s8v*)(w2tl + ((mtg3 + p) * 16 + lm) * HID + jo);
        #pragma unroll
        for (int q = 0; q < 4; ++q)
          B[q] = *(const s8v*)&sGb[((ntg4 + q) * 16 + lm) * EST + jo];
        #pragma unroll
        for (int p = 0; p < 3; ++p)
          #pragma unroll
          for (int q = 0; q < 4; ++q)
            acc[p][q] = MFMA16(A[p], B[q], acc[p][q]);
      }
      float pz[4][6];
      #pragma unroll
      for (int q = 0; q < 4; ++q)
        #pragma unroll
        for (int i = 0; i < 6; ++i) pz[q][i] = 0.f;
      #pragma unroll
      for (int p = 0; p < 3; ++p) {
        int kb = (mtg3 + p) * 16 + lq * 4;
        float w1v[4][6];
        #pragma unroll
        for (int rg = 0; rg < 4; ++rg) {
          uint4 wr = *(const uint4*)(smraw + OB_W1 + (kb + rg) * 16);
          w1v[rg][0] = blo(wr.x); w1v[rg][1] = bhi(wr.x);
          w1v[rg][2] = blo(wr.y); w1v[rg][3] = bhi(wr.y);
          w1v[rg][4] = blo(wr.z); w1v[rg][5] = bhi(wr.z);
        }
        #pragma unroll
        for (int q = 0; q < 4; ++q) {
          int e31 = (((ntg4 + q) & 1) << 4) + lm;   // col & 31
          const unsigned* mp = (const unsigned*)&sH1b[e31 * EST + kb];
          unsigned mm0 = mp[0], mm1 = mp[1];
          unsigned short hb[4] = {
            (unsigned short)(mm0 & 0xffff), (unsigned short)(mm0 >> 16),
            (unsigned short)(mm1 & 0xffff), (unsigned short)(mm1 >> 16)};
          #pragma unroll
          for (int rg = 0; rg < 4; ++rg) {
            float val = hb[rg] ? acc[p][q][rg] : 0.f;
            #pragma unroll
            for (int i = 0; i < 6; ++i)
              pz[q][i] = fmaf(w1v[rg][i], val, pz[q][i]);
          }
        }
      }
      #pragma unroll
      for (int q = 0; q < 4; ++q)
        #pragma unroll
        for (int i = 0; i < 6; ++i) {
          float v = pz[q][i];
          v += __shfl_xor(v, 16);
          v += __shfl_xor(v, 32);
          if (lane < 16) atomicAdd(&sGZ[i * 192 + (ntg4 + q) * 16 + lane], v);
        }
    }
    __syncthreads();
  }

  // ---- final V5 (layer 0, parity 0) + z/lp; then jp writeback ----
  {
    float* prv0 = sPRM;                             // (0 & 1) == 0
    for (int idx = tid; idx < 1152; idx += 768) {
      int i = idx / 192, rem = idx - i * 192;
      int r = rem >> 5, e5 = rem & 31;
      float r1  = sR[(r * 12 + i) * EPB + e5];
      float r2o = sR[(r * 12 + 6 + i) * EPB + e5];
      float es  = prv0[(2 * i + 1) * EPB + e5];
      sR[(r * 12 + i) * EPB + e5]     = r2o + sGZ[i * 192 + rem];
      sR[(r * 12 + 6 + i) * EPB + e5] = r1 * es;
    }
  }
  if (tid < 192) {
    int i = grp;
    yz[(blk * EPB + e) * 12 + i]     = z_a;
    yz[(blk * EPB + e) * 12 + 6 + i] = z_b;
    atomicAdd(&sZQ[e], fmaf(z_a, z_a, z_b * z_b));
  }
  __syncthreads();
  if (tid < 32)
    out_lp[blk * EPB + tid] = sLD[tid] - 11.027262398456072f - 0.5f * sZQ[tid];

  float part = 0.f;
  for (int idx = tid; idx < 72 * EPB; idx += 768) {
    int rt = idx >> 5, ee = idx & 31;
    float v = sR[idx];
    jp[(blk * EPB + ee) * 72 + rt] = v;
    part = fmaf(v, v, part);
  }
  #pragma unroll
  for (int off = 32; off > 0; off >>= 1) part += __shfl_down(part, off, 64);
  if ((tid & 63) == 0) atomicAdd(&sRed[0], part);
  __syncthreads();
  if (tid == 0) atomicAdd(ws_sum, sRed[0]);
}

// ---------------------------------------------------------------------
// kl_kernel: one thread per element (unchanged from R3..R11 PASS).
__global__ __launch_bounds__(256) void kl_kernel(
    const float* __restrict__ zin, const float* __restrict__ jpin,
    const float* __restrict__ Wsym, const float* __restrict__ lvd,
    const float* __restrict__ ws_sum, float* __restrict__ out_kl) {
  int elem = blockIdx.x * 256 + threadIdx.x;
  float z[12];
  #pragma unroll
  for (int i = 0; i < 12; ++i) z[i] = zin[elem * 12 + i];
  float scale = 1.0f / sqrtf(ws_sum[0]);
  float Jp[6][12];
  #pragma unroll
  for (int n = 0; n < 6; ++n)
    #pragma unroll
    for (int j = 0; j < 12; ++j)
      Jp[n][j] = jpin[elem * 72 + n * 12 + j] * scale;

  float Sq[78];
  #pragma unroll
  for (int i = 0; i < 78; ++i) Sq[i] = 0.f;
  float tq = 0.f, tpq = 0.f;

  for (int m = 0; m < NBASE; ++m) {
    const float* Wm = Wsym + m * 144;
    float jq[12];
    #pragma unroll
    for (int j = 0; j < 12; ++j) {
      float acc = 0.f;
      #pragma unroll
      for (int i = 0; i < 12; ++i)
        acc = fmaf(Wm[j * 12 + i] - Wm[i * 12 + j], z[i], acc);
      jq[j] = acc;
    }
    #pragma unroll
    for (int i = 0; i < 12; ++i) {
      tq = fmaf(jq[i], jq[i], tq);
      #pragma unroll
      for (int j = 0; j <= i; ++j)
        Sq[i * (i + 1) / 2 + j] = fmaf(jq[i], jq[j], Sq[i * (i + 1) / 2 + j]);
    }
    #pragma unroll
    for (int n = 0; n < 6; ++n) {
      float d = 0.f;
      #pragma unroll
      for (int j = 0; j < 12; ++j) d = fmaf(Jp[n][j], jq[j], d);
      tpq = fmaf(d, d, tpq);
    }
  }

  float Dv[12], Db[12];
  #pragma unroll
  for (int j = 0; j < 12; ++j) Dv[j] = expf(-lvd[j]);

  float mh = 0.f;
  #pragma unroll
  for (int i = 0; i < 12; ++i) mh += Sq[i * (i + 1) / 2 + i] + Dv[i];
  float norm_H = fmaxf(mh * (1.f / 12.f), 1e-6f);
  #pragma unroll
  for (int i = 0; i < 12; ++i) Sq[i * (i + 1) / 2 + i] += Dv[i] + 1e-3f * norm_H;
  float sumDb = 0.f;
  #pragma unroll
  for (int j = 0; j < 12; ++j) { Db[j] = Dv[j] + 1e-3f * norm_H; sumDb += Db[j]; }

  float M[21];
  #pragma unroll
  for (int n = 0; n < 6; ++n)
    #pragma unroll
    for (int mm = 0; mm <= n; ++mm) {
      float acc = 0.f;
      #pragma unroll
      for (int j = 0; j < 12; ++j) acc = fmaf(Jp[n][j], Jp[mm][j], acc);
      M[n * (n + 1) / 2 + mm] = acc;
    }
  float md = 0.f;
  #pragma unroll
  for (int i = 0; i < 6; ++i) md += M[i * (i + 1) / 2 + i];
  float norm_M = fmaxf(md * (1.f / 6.f) + EPSP, 1e-6f);
  #pragma unroll
  for (int i = 0; i < 6; ++i) M[i * (i + 1) / 2 + i] += EPSP + 1e-3f * norm_M;

  float trace_p = 0.f;
  #pragma unroll
  for (int n = 0; n < 6; ++n)
    #pragma unroll
    for (int j = 0; j < 12; ++j)
      trace_p = fmaf(Jp[n][j] * Jp[n][j], Db[j], trace_p);

  float trace = (EPSP + 1e-3f * norm_M) * (sumDb + tq) + trace_p + tpq;

  float ldM = 0.f;
  #pragma unroll
  for (int jc = 0; jc < 6; ++jc) {
    float d = M[jc * (jc + 1) / 2 + jc];
    #pragma unroll
    for (int k = 0; k < jc; ++k) d -= M[jc * (jc + 1) / 2 + k] * M[jc * (jc + 1) / 2 + k];
    d = sqrtf(d);
    ldM += logf(d);
    float di = 1.f / d;
    M[jc * (jc + 1) / 2 + jc] = d;
    #pragma unroll
    for (int i2 = jc + 1; i2 < 6; ++i2) {
      float v = M[i2 * (i2 + 1) / 2 + jc];
      #pragma unroll
      for (int k = 0; k < jc; ++k) v -= M[i2 * (i2 + 1) / 2 + k] * M[jc * (jc + 1) / 2 + k];
      M[i2 * (i2 + 1) / 2 + jc] = v * di;
    }
  }

  float ldH = 0.f;
  #pragma unroll
  for (int jc = 0; jc < 12; ++jc) {
    float d = Sq[jc * (jc + 1) / 2 + jc];
    #pragma unroll
    for (int k = 0; k < jc; ++k) d -= Sq[jc * (jc + 1) / 2 + k] * Sq[jc * (jc + 1) / 2 + k];
    d = sqrtf(d);
    ldH += logf(d);
    float di = 1.f / d;
    Sq[jc * (jc + 1) / 2 + jc] = d;
    #pragma unroll
    for (int i2 = jc + 1; i2 < 12; ++i2) {
      float v = Sq[i2 * (i2 + 1) / 2 + jc];
      #pragma unroll
      for (int k = 0; k < jc; ++k) v -= Sq[i2 * (i2 + 1) / 2 + k] * Sq[jc * (jc + 1) / 2 + k];
      Sq[i2 * (i2 + 1) / 2 + jc] = v * di;
    }
  }

  float logdet_p = 2.f * ldM + 6.f * logf(EPSP);
  float logdet_q = 2.f * ldH;
  out_kl[elem] = 0.5f * (trace - (logdet_p + logdet_q) - 12.f);
}

// ---------------------------------------------------------------------
extern "C" void kernel_launch(void* const* d_in, const int* in_sizes, int n_in,
                              void* d_out, int out_size, void* d_ws, size_t ws_size,
                              hipStream_t stream) {
  (void)in_sizes; (void)n_in; (void)out_size; (void)ws_size;
  float* y    = (float*)d_in[0];   // consumed, then overwritten with z
  float* Jp   = (float*)d_in[1];   // consumed, then overwritten with pullback Jp
  const float* W1   = (const float*)d_in[2];
  const float* b1   = (const float*)d_in[3];
  const float* W2   = (const float*)d_in[4];
  const float* b2   = (const float*)d_in[5];
  const float* W3   = (const float*)d_in[6];
  const float* b3   = (const float*)d_in[7];
  const float* Wsym = (const float*)d_in[8];
  const float* lvd  = (const float*)d_in[9];
  float* out = (float*)d_out;      // fp32: [log_prob (B), kl (B)]

  float* ws_sum = (float*)d_ws;
  unsigned short* w2b = (unsigned short*)((char*)d_ws + 256);
  unsigned short* w2t = (unsigned short*)((char*)d_ws + 256 +
                                          NLAYER * HID * HID * 2);
  hipMemsetAsync(d_ws, 0, 4, stream);

  hipFuncSetAttribute((const void*)flow_kernel,
                      hipFuncAttributeMaxDynamicSharedMemorySize, SMEM_BYTES);

  prep_kernel<<<3456, 256, 0, stream>>>(W2, w2b, w2t);
  flow_kernel<<<BTOT / EPB, 768, SMEM_BYTES, stream>>>(
      y, Jp, W1, b1, b2, W3, b3, w2b, w2t, ws_sum, out);
  kl_kernel<<<64, 256, 0, stream>>>(y, Jp, Wsym, lvd, ws_sum, out + BTOT);
}